// Round 3
// baseline (861.601 us; speedup 1.0000x reference)
//
#include <hip/hip_runtime.h>
#include <stdint.h>
#include <math.h>

// ---------------------------------------------------------------------------
// DepthPriorLoss — single persistent kernel, v2.
// vs round 2: 1024-thread blocks (16 waves/CU), 15-bit coarse radix level +
// small-list exact select (5 full-array passes, 6 grid barriers instead of
// 8 passes / 9 barriers). All value-visible math identical to the passing
// round-1 implementation (bit-exact outputs).
// ---------------------------------------------------------------------------

#define NB 256
#define NT 1024
#define NALL (NB * NT)
#define MAGICV 0x5A17CAFEu
#define LCAP 32768u

enum : uint32_t {
  W_BCNT = 0, W_BGEN = 1, W_MAGIC = 2, W_ZDONE = 3,
  W_CNT      = 4,        // 4 list counters (A1,B1,A2,B2)
  W_PERCOUNT = 16,       // uint32[256]
  W_COUNTS   = 272,      // int[1000]
  W_PERLOSS  = 1272,     // double[256] (byte 5088, 8-aligned)
  W_SCALES   = 1784,     // float[1000]
  W_SHIFTS   = 2784,     // float[1000]
  W_XSUB     = 3784,     // float[50000]
  W_YSUB     = 53784,    // float[50000]
  W_G1       = 103808,   // uint32[16384] coarse hist (bins = (u>>17)&16383)
  W_G2       = 120192,   // uint32[16384]
  W_LA1      = 136576,   // uint32[32768]
  W_LB1      = 169344,
  W_LA2      = 202112,
  W_LB2      = 234880,
  W_UT       = 267648    // uint32[P] (byte 1070592, 16B aligned)
};

// ---------------- threefry2x32 (JAX-exact, partitionable mode) -------------
__device__ __forceinline__ uint32_t rotl32(uint32_t v, int d) {
  return (v << d) | (v >> (32 - d));
}
__device__ __forceinline__ void tf2x32(uint32_t k0, uint32_t k1,
                                       uint32_t c0, uint32_t c1,
                                       uint32_t& o0, uint32_t& o1) {
  uint32_t ks2 = k0 ^ k1 ^ 0x1BD11BDAu;
  uint32_t x0 = c0 + k0;
  uint32_t x1 = c1 + k1;
#define TFR(r) { x0 += x1; x1 = rotl32(x1, r); x1 ^= x0; }
  TFR(13) TFR(15) TFR(26) TFR(6)
  x0 += k1;  x1 += ks2 + 1u;
  TFR(17) TFR(29) TFR(16) TFR(24)
  x0 += ks2; x1 += k0 + 2u;
  TFR(13) TFR(15) TFR(26) TFR(6)
  x0 += k0;  x1 += k1 + 3u;
  TFR(17) TFR(29) TFR(16) TFR(24)
  x0 += k1;  x1 += ks2 + 4u;
  TFR(13) TFR(15) TFR(26) TFR(6)
  x0 += ks2; x1 += k0 + 5u;
#undef TFR
  o0 = x0; o1 = x1;
}
struct Keys { uint32_t hp0, hp1, lp0, lp1, hs0, hs1, ls0, ls1; };
__device__ __forceinline__ Keys derive_keys() {
  Keys K; uint32_t p0, p1, q0, q1;
  tf2x32(0u, 42u, 0u, 0u, p0, p1);
  tf2x32(0u, 42u, 0u, 1u, q0, q1);
  tf2x32(p0, p1, 0u, 0u, K.hp0, K.hp1);
  tf2x32(p0, p1, 0u, 1u, K.lp0, K.lp1);
  tf2x32(q0, q1, 0u, 0u, K.hs0, K.hs1);
  tf2x32(q0, q1, 0u, 1u, K.ls0, K.ls1);
  return K;
}
__device__ __forceinline__ uint32_t bits32(uint32_t k0, uint32_t k1, uint32_t e) {
  uint32_t a, b; tf2x32(k0, k1, 0u, e, a, b); return a ^ b;
}
__device__ __forceinline__ uint32_t ri_offset(uint32_t hi, uint32_t lo, uint32_t span) {
  uint32_t m = 65536u % span;
  m = (m * m) % span;
  uint32_t off = (hi % span) * m + (lo % span);
  return off % span;
}

// ---------------- order-preserving float<->uint ----------------------------
__device__ __forceinline__ uint32_t f2u(float f) {
  uint32_t u = __float_as_uint(f);
  return (u & 0x80000000u) ? ~u : (u | 0x80000000u);
}
__device__ __forceinline__ float u2f(uint32_t u) {
  uint32_t v = (u & 0x80000000u) ? (u & 0x7FFFFFFFu) : ~u;
  return __uint_as_float(v);
}

// ---------------- grid barrier (proven in round 2) -------------------------
__device__ __forceinline__ void gridbar(uint32_t* ws32) {
  __syncthreads();
  if (threadIdx.x == 0) {
    __threadfence();
    uint32_t g = __hip_atomic_load(&ws32[W_BGEN], __ATOMIC_RELAXED,
                                   __HIP_MEMORY_SCOPE_AGENT);
    uint32_t old = __hip_atomic_fetch_add(&ws32[W_BCNT], 1u, __ATOMIC_ACQ_REL,
                                          __HIP_MEMORY_SCOPE_AGENT);
    if (old == (uint32_t)(NB - 1)) {
      __hip_atomic_store(&ws32[W_BCNT], 0u, __ATOMIC_RELAXED,
                         __HIP_MEMORY_SCOPE_AGENT);
      __hip_atomic_store(&ws32[W_BGEN], g + 1u, __ATOMIC_RELEASE,
                         __HIP_MEMORY_SCOPE_AGENT);
    } else {
      while (__hip_atomic_load(&ws32[W_BGEN], __ATOMIC_ACQUIRE,
                               __HIP_MEMORY_SCOPE_AGENT) == g) {
        __builtin_amdgcn_s_sleep(2);
      }
    }
    __threadfence();
  }
  __syncthreads();
}

// ---------------- selection primitives -------------------------------------
// Block-wide exclusive prefix sum (1024 threads, 16 waves).
__device__ __forceinline__ uint32_t block_excl(uint32_t local, uint32_t* wtot) {
  const int tid = threadIdx.x, lane = tid & 63, wid = tid >> 6;
  __syncthreads();                       // protect wtot reuse
  uint32_t v = local;
#pragma unroll
  for (int off = 1; off < 64; off <<= 1) {
    uint32_t o = __shfl_up(v, off);
    if (lane >= off) v += o;
  }
  if (lane == 63) wtot[wid] = v;
  __syncthreads();
  uint32_t base = 0;
  for (int w = 0; w < 16; w++) if (w < wid) base += wtot[w];
  return base + v - local;
}

// Rank-select over the 16384-bin global u32 hist. Result in bc[0]=bin,bc[1]=rk'.
__device__ void g_select(const uint32_t* __restrict__ G, uint32_t rk,
                         uint32_t* wtot, uint32_t* bc) {
  const int tid = threadIdx.x;
  const int base = tid * 16;
  uint32_t local = 0;
#pragma unroll
  for (int k = 0; k < 16; k++) local += G[base + k];
  uint32_t excl = block_excl(local, wtot);
  if (local > 0 && rk >= excl && rk < excl + local) {
    uint32_t c = excl;
    for (int k = 0; k < 16; k++) {
      uint32_t v = G[base + k];
      if (rk < c + v) { bc[0] = (uint32_t)(base + k); bc[1] = rk - c; break; }
      c += v;
    }
  }
  __syncthreads();
}

// Rank-select over an LDS hist with nbins<=1024 (one bin per thread).
__device__ void small_select(const uint32_t* h, int nbins, uint32_t rk,
                             uint32_t* wtot, uint32_t* bc) {
  const int tid = threadIdx.x;
  uint32_t local = (tid < nbins) ? h[tid] : 0u;
  uint32_t excl = block_excl(local, wtot);
  if (local > 0 && rk >= excl && rk < excl + local) {
    bc[0] = (uint32_t)tid; bc[1] = rk - excl;
  }
  __syncthreads();
}

// Exact rank-rk element of `list` (cnt entries, all sharing coarse bin15).
// Resolves the remaining 17 bits via 9-bit + 8-bit LDS hist levels.
__device__ uint32_t list_select(const uint32_t* __restrict__ list, uint32_t cnt,
                                uint32_t rk, uint32_t bin15, uint32_t* smem,
                                uint32_t* wtot, uint32_t* bc, uint32_t* tcnt) {
  const int tid = threadIdx.x;
  uint32_t* histA = smem;          // 512 bins: value bits [16:8]
  uint32_t* histB = smem + 512;    // 256 bins: value bits [7:0]
  uint32_t* tiny  = smem + 1024;   // up to 2048 collected values
  __syncthreads();
  for (int i = tid; i < 768; i += NT) smem[i] = 0;
  if (tid == 0) *tcnt = 0;
  __syncthreads();
  for (uint32_t i = tid; i < cnt; i += NT)
    atomicAdd(&histA[(list[i] >> 8) & 511u], 1u);
  __syncthreads();
  small_select(histA, 512, rk, wtot, bc);
  uint32_t binA = bc[0], rk2 = bc[1];
  for (uint32_t i = tid; i < cnt; i += NT) {
    uint32_t v = list[i];
    if (((v >> 8) & 511u) == binA) {
      uint32_t j = atomicAdd(tcnt, 1u);
      if (j < 2048u) tiny[j] = v;
    }
  }
  __syncthreads();
  uint32_t m = *tcnt; if (m > 2048u) m = 2048u;
  for (uint32_t i = tid; i < m; i += NT) atomicAdd(&histB[tiny[i] & 255u], 1u);
  __syncthreads();
  small_select(histB, 256, rk2, wtot, bc);
  uint32_t binB = bc[0];
  __syncthreads();
  return ((16384u + bin15) << 17) | (binA << 8) | binB;
}

// M2 transform: ut value -> f2u(|y - med|), invalid stays last.
__device__ __forceinline__ uint32_t m2w(uint32_t u, float med) {
  return (u != 0xFFFFFFFFu) ? f2u(fabsf(__fsub_rn(u2f(u), med))) : 0xFFFFFFFFu;
}

// ---------------- the mega-kernel ------------------------------------------
__global__ __launch_bounds__(1024) void mega(const float* __restrict__ dren,
                                             const float* __restrict__ dpri,
                                             float* __restrict__ out,
                                             uint32_t* __restrict__ WS, int P) {
  const int tid = threadIdx.x, bid = blockIdx.x;
  const int gid = bid * NT + tid;
  const int lane = tid & 63, wid = tid >> 6;

  float* out_y     = out + 1;
  float* out_depth = out + 1 + P;
  uint32_t* ut     = WS + W_UT;

  __shared__ uint32_t smem[8192];   // 32 KB: packed-u16 coarse hist / select scratch
  __shared__ uint32_t wtot[16];
  __shared__ uint32_t bc[2];
  __shared__ uint32_t tcntS;
  __shared__ uint32_t ubcast;
  __shared__ float    fbcast[2];
  __shared__ int      ired[128];
  __shared__ double   dred[16];

  // ---- init: block 0 arms barrier words, everyone zeros a hist slice ----
  if (bid == 0 && tid == 0) {
    WS[W_BCNT] = 0u; WS[W_BGEN] = 0u; WS[W_ZDONE] = 0u;
    __threadfence();
    __hip_atomic_store(&WS[W_MAGIC], MAGICV, __ATOMIC_RELEASE,
                       __HIP_MEMORY_SCOPE_AGENT);
  }
  if (tid < 128) WS[W_G1 + bid * 128 + tid] = 0u;   // covers G1+G2 (256*128=32768)
  if (bid == 0) {
    for (int k = tid; k < 1000; k += NT) WS[W_COUNTS + k] = 0u;
    if (tid < 4) WS[W_CNT + tid] = 0u;
  }
  if (tid == 0) {
    while (__hip_atomic_load(&WS[W_MAGIC], __ATOMIC_ACQUIRE,
                             __HIP_MEMORY_SCOPE_AGENT) != MAGICV) {
      __builtin_amdgcn_s_sleep(2);
    }
  }
  __syncthreads();
  if (tid == 0) {
    __threadfence();   // publish slice zeroing before signaling done
    __hip_atomic_fetch_add(&WS[W_ZDONE], 1u, __ATOMIC_ACQ_REL,
                           __HIP_MEMORY_SCOPE_AGENT);
  }

  // ==== P1: elemwise (y, ut, valid count) + fused coarse hist ====
  for (int i = tid; i < 8192; i += NT) smem[i] = 0u;
  __syncthreads();
  {
    int cnt = 0;
    const float4* d4 = (const float4*)dren;
    uint4* ut4 = (uint4*)ut;
    const int P4 = P >> 2;
    for (int i = gid; i < P4; i += NALL) {
      float4 d = d4[i];
      float dc[4] = { d.x, d.y, d.z, d.w };
      float yv[4]; uint32_t uv[4];
#pragma unroll
      for (int k = 0; k < 4; k++) {
        float dv = dc[k];
        float y = __fdiv_rn(1.0f, __fadd_rn(dv, 1e-6f));
        bool m = (dv > 0.1f) && (dv < 100.0f) && isfinite(dv);
        cnt += m ? 1 : 0;
        yv[k] = y;
        uv[k] = m ? f2u(y) : 0xFFFFFFFFu;
        uint32_t bin = (uv[k] >> 17) & 16383u;
        atomicAdd(&smem[bin >> 1], 1u << ((bin & 1u) << 4));
      }
      out_y[4 * i + 0] = yv[0]; out_y[4 * i + 1] = yv[1];
      out_y[4 * i + 2] = yv[2]; out_y[4 * i + 3] = yv[3];
      uint4 q; q.x = uv[0]; q.y = uv[1]; q.z = uv[2]; q.w = uv[3];
      ut4[i] = q;
    }
    for (int i = (P & ~3) + gid; i < P; i += NALL) {
      float dv = dren[i];
      float y = __fdiv_rn(1.0f, __fadd_rn(dv, 1e-6f));
      bool m = (dv > 0.1f) && (dv < 100.0f) && isfinite(dv);
      cnt += m ? 1 : 0;
      out_y[i] = y;
      uint32_t u = m ? f2u(y) : 0xFFFFFFFFu;
      ut[i] = u;
      uint32_t bin = (u >> 17) & 16383u;
      atomicAdd(&smem[bin >> 1], 1u << ((bin & 1u) << 4));
    }
    for (int off = 32; off > 0; off >>= 1) cnt += __shfl_down(cnt, off);
    if (lane == 0) ired[wid] = cnt;
  }
  // wait: all blocks done zeroing the global hists
  __syncthreads();
  if (tid == 0) {
    while (__hip_atomic_load(&WS[W_ZDONE], __ATOMIC_ACQUIRE,
                             __HIP_MEMORY_SCOPE_AGENT) != (uint32_t)NB) {
      __builtin_amdgcn_s_sleep(2);
    }
    __threadfence();
  }
  __syncthreads();
  // flush packed LDS hist -> G1, store per-block valid count
  for (int w = tid; w < 8192; w += NT) {
    uint32_t pv = smem[w];
    if (pv) {
      uint32_t lo = pv & 0xFFFFu, hi = pv >> 16;
      if (lo) atomicAdd(&WS[W_G1 + 2 * w], lo);
      if (hi) atomicAdd(&WS[W_G1 + 2 * w + 1], hi);
    }
  }
  if (tid == 0)
    WS[W_PERCOUNT + bid] = (uint32_t)(ired[0] + ired[1] + ired[2] + ired[3] +
                                      ired[4] + ired[5] + ired[6] + ired[7] +
                                      ired[8] + ired[9] + ired[10] + ired[11] +
                                      ired[12] + ired[13] + ired[14] + ired[15]);
  gridbar(WS);   // B1

  // ==== n + ranks (redundant per block) ====
  uint32_t n;
  {
    uint32_t v = (tid < 256) ? WS[W_PERCOUNT + tid] : 0u;
    for (int off = 32; off > 0; off >>= 1) v += __shfl_down(v, off);
    if (lane == 0) wtot[wid] = v;
    __syncthreads();
    if (tid == 0) {
      uint32_t s = 0;
      for (int w = 0; w < 16; w++) s += wtot[w];
      ubcast = s;
    }
    __syncthreads();
    n = ubcast;
    __syncthreads();
  }
  const uint32_t nn = n ? n : 1u;
  const uint32_t kA = (nn - 1u) >> 1, kB = nn >> 1;

  // ==== R1: coarse bins for median(y); pairs + subs; M1 collect ====
  uint32_t binA1, rkA1, binB1, rkB1;
  g_select(WS + W_G1, kA, wtot, bc); binA1 = bc[0]; rkA1 = bc[1];
  g_select(WS + W_G1, kB, wtot, bc); binB1 = bc[0]; rkB1 = bc[1];
  const bool dv1 = (binA1 != binB1);
  {
    float* scales = (float*)(WS + W_SCALES);
    float* shifts = (float*)(WS + W_SHIFTS);
    float* x_sub  = (float*)(WS + W_XSUB);
    float* y_sub  = (float*)(WS + W_YSUB);
    uint32_t span = n ? n : 1u;
    if (gid < 1000) {
      Keys K = derive_keys();
      uint32_t hi0 = bits32(K.hp0, K.hp1, (uint32_t)(2 * gid));
      uint32_t lo0 = bits32(K.lp0, K.lp1, (uint32_t)(2 * gid));
      uint32_t hi1 = bits32(K.hp0, K.hp1, (uint32_t)(2 * gid + 1));
      uint32_t lo1 = bits32(K.lp0, K.lp1, (uint32_t)(2 * gid + 1));
      uint32_t i0 = ri_offset(hi0, lo0, span);
      uint32_t i1 = ri_offset(hi1, lo1, span);
      float x1v = dpri[i0], y1v = out_y[i0];
      float x2v = dpri[i1], y2v = out_y[i1];
      float sc = __fdiv_rn(__fsub_rn(y2v, y1v),
                           __fadd_rn(__fsub_rn(x2v, x1v), 1e-8f));
      scales[gid] = sc;
      shifts[gid] = __fsub_rn(y1v, __fmul_rn(sc, x1v));
    }
    if (gid < 50000) {
      Keys K = derive_keys();
      uint32_t hi = bits32(K.hs0, K.hs1, (uint32_t)gid);
      uint32_t lo = bits32(K.ls0, K.ls1, (uint32_t)gid);
      uint32_t idx = ri_offset(hi, lo, span);
      x_sub[gid] = dpri[idx];
      y_sub[gid] = out_y[idx];
    }
    // M1 collect: gather elements of selected coarse bins into global lists
    uint32_t* LA = WS + W_LA1; uint32_t* LB = WS + W_LB1;
    const uint4* u4 = (const uint4*)ut;
    const int P4 = P >> 2;
    for (int i = gid; i < P4; i += NALL) {
      uint4 q = u4[i];
      uint32_t e[4] = { q.x, q.y, q.z, q.w };
#pragma unroll
      for (int k = 0; k < 4; k++) {
        uint32_t b = (e[k] >> 17) & 16383u;
        if (b == binA1) {
          uint32_t j = atomicAdd(&WS[W_CNT + 0], 1u);
          if (j < LCAP) LA[j] = e[k];
        } else if (dv1 && b == binB1) {
          uint32_t j = atomicAdd(&WS[W_CNT + 1], 1u);
          if (j < LCAP) LB[j] = e[k];
        }
      }
    }
    for (int i = (P & ~3) + gid; i < P; i += NALL) {
      uint32_t u = ut[i];
      uint32_t b = (u >> 17) & 16383u;
      if (b == binA1) {
        uint32_t j = atomicAdd(&WS[W_CNT + 0], 1u);
        if (j < LCAP) LA[j] = u;
      } else if (dv1 && b == binB1) {
        uint32_t j = atomicAdd(&WS[W_CNT + 1], 1u);
        if (j < LCAP) LB[j] = u;
      }
    }
  }
  gridbar(WS);   // B2

  // ==== R2: exact median(y); then M2 coarse hist ====
  float med;
  {
    uint32_t cA = WS[W_CNT + 0]; if (cA > LCAP) cA = LCAP;
    uint32_t vA = list_select(WS + W_LA1, cA, rkA1, binA1, smem, wtot, bc, &tcntS);
    uint32_t vB;
    if (dv1) {
      uint32_t cB = WS[W_CNT + 1]; if (cB > LCAP) cB = LCAP;
      vB = list_select(WS + W_LB1, cB, rkB1, binB1, smem, wtot, bc, &tcntS);
    } else {
      vB = list_select(WS + W_LA1, cA, rkB1, binA1, smem, wtot, bc, &tcntS);
    }
    med = __fmul_rn(__fadd_rn(u2f(vA), u2f(vB)), 0.5f);
  }
  __syncthreads();
  for (int i = tid; i < 8192; i += NT) smem[i] = 0u;
  __syncthreads();
  {
    const uint4* u4 = (const uint4*)ut;
    const int P4 = P >> 2;
    for (int i = gid; i < P4; i += NALL) {
      uint4 q = u4[i];
      uint32_t e[4] = { q.x, q.y, q.z, q.w };
#pragma unroll
      for (int k = 0; k < 4; k++) {
        uint32_t w = m2w(e[k], med);
        uint32_t bin = (w >> 17) & 16383u;
        atomicAdd(&smem[bin >> 1], 1u << ((bin & 1u) << 4));
      }
    }
    for (int i = (P & ~3) + gid; i < P; i += NALL) {
      uint32_t w = m2w(ut[i], med);
      uint32_t bin = (w >> 17) & 16383u;
      atomicAdd(&smem[bin >> 1], 1u << ((bin & 1u) << 4));
    }
    __syncthreads();
    for (int w = tid; w < 8192; w += NT) {
      uint32_t pv = smem[w];
      if (pv) {
        uint32_t lo = pv & 0xFFFFu, hi = pv >> 16;
        if (lo) atomicAdd(&WS[W_G2 + 2 * w], lo);
        if (hi) atomicAdd(&WS[W_G2 + 2 * w + 1], hi);
      }
    }
  }
  gridbar(WS);   // B3

  // ==== R3: coarse bins for median(|y-med|); M2 collect ====
  uint32_t binA2, rkA2, binB2, rkB2;
  g_select(WS + W_G2, kA, wtot, bc); binA2 = bc[0]; rkA2 = bc[1];
  g_select(WS + W_G2, kB, wtot, bc); binB2 = bc[0]; rkB2 = bc[1];
  const bool dv2 = (binA2 != binB2);
  {
    uint32_t* LA = WS + W_LA2; uint32_t* LB = WS + W_LB2;
    const uint4* u4 = (const uint4*)ut;
    const int P4 = P >> 2;
    for (int i = gid; i < P4; i += NALL) {
      uint4 q = u4[i];
      uint32_t e[4] = { q.x, q.y, q.z, q.w };
#pragma unroll
      for (int k = 0; k < 4; k++) {
        uint32_t w = m2w(e[k], med);
        uint32_t b = (w >> 17) & 16383u;
        if (b == binA2) {
          uint32_t j = atomicAdd(&WS[W_CNT + 2], 1u);
          if (j < LCAP) LA[j] = w;
        } else if (dv2 && b == binB2) {
          uint32_t j = atomicAdd(&WS[W_CNT + 3], 1u);
          if (j < LCAP) LB[j] = w;
        }
      }
    }
    for (int i = (P & ~3) + gid; i < P; i += NALL) {
      uint32_t w = m2w(ut[i], med);
      uint32_t b = (w >> 17) & 16383u;
      if (b == binA2) {
        uint32_t j = atomicAdd(&WS[W_CNT + 2], 1u);
        if (j < LCAP) LA[j] = w;
      } else if (dv2 && b == binB2) {
        uint32_t j = atomicAdd(&WS[W_CNT + 3], 1u);
        if (j < LCAP) LB[j] = w;
      }
    }
  }
  gridbar(WS);   // B4

  // ==== R4: dyn; RANSAC scoring ====
  float dyn;
  {
    uint32_t cA = WS[W_CNT + 2]; if (cA > LCAP) cA = LCAP;
    uint32_t wA = list_select(WS + W_LA2, cA, rkA2, binA2, smem, wtot, bc, &tcntS);
    uint32_t wB;
    if (dv2) {
      uint32_t cB = WS[W_CNT + 3]; if (cB > LCAP) cB = LCAP;
      wB = list_select(WS + W_LB2, cB, rkB2, binB2, smem, wtot, bc, &tcntS);
    } else {
      wB = list_select(WS + W_LA2, cA, rkB2, binA2, smem, wtot, bc, &tcntS);
    }
    float mad = __fmul_rn(__fadd_rn(u2f(wA), u2f(wB)), 0.5f);
    dyn = __fmul_rn(mad, 0.5f);
    if (dyn < 1e-5f) dyn = 0.01f;   // THRESH
  }
  {
    // 125 candidate groups x 2 sub-halves; blocks 0..249 participate
    const float* scales = (const float*)(WS + W_SCALES);
    const float* shifts = (const float*)(WS + W_SHIFTS);
    const float* x_sub  = (const float*)(WS + W_XSUB);
    const float* y_sub  = (const float*)(WS + W_YSUB);
    int* counts = (int*)(WS + W_COUNTS);
    if (bid < 250) {
      const int cg = bid >> 1, half = bid & 1;
      const int cbase = cg * 8;
      const int e0 = half * 25000, e1 = e0 + 25000;
      float ss[8], tt[8]; int c[8];
#pragma unroll
      for (int j = 0; j < 8; j++) { ss[j] = scales[cbase + j]; tt[j] = shifts[cbase + j]; c[j] = 0; }
      for (int e = e0 + tid; e < e1; e += NT) {
        float xe = x_sub[e], ye = y_sub[e];
#pragma unroll
        for (int j = 0; j < 8; j++) {
          float r = fabsf(__fsub_rn(__fadd_rn(__fmul_rn(ss[j], xe), tt[j]), ye));
          c[j] += (r < dyn) ? 1 : 0;
        }
      }
#pragma unroll
      for (int j = 0; j < 8; j++) {
        int v = c[j];
        for (int off = 32; off > 0; off >>= 1) v += __shfl_down(v, off);
        if (lane == 0) ired[wid * 8 + j] = v;
      }
      __syncthreads();
      if (tid < 8) {
        int tot = 0;
        for (int w = 0; w < 16; w++) tot += ired[w * 8 + tid];
        atomicAdd(&counts[cbase + tid], tot);
      }
    }
  }
  gridbar(WS);   // B5

  // ==== argmax (redundant) + final elemwise + loss partials ====
  {
    const int* counts = (const int*)(WS + W_COUNTS);
    const float* scales = (const float*)(WS + W_SCALES);
    const float* shifts = (const float*)(WS + W_SHIFTS);
    int cc = -2, ci = 0x7FFFFFFF;
    if (tid < 1000) {
      cc = counts[tid];
      if (!(scales[tid] > 0.0f)) cc = -1;
      ci = tid;
    }
    for (int off = 32; off > 0; off >>= 1) {
      int oc = __shfl_down(cc, off), oi = __shfl_down(ci, off);
      if (oc > cc || (oc == cc && oi < ci)) { cc = oc; ci = oi; }
    }
    if (lane == 0) { ired[wid] = cc; ired[16 + wid] = ci; }
    __syncthreads();
    if (tid == 0) {
      int bcn = ired[0], bix = ired[16];
      for (int w = 1; w < 16; w++) {
        if (ired[w] > bcn || (ired[w] == bcn && ired[16 + w] < bix)) {
          bcn = ired[w]; bix = ired[16 + w];
        }
      }
      bool valid = bcn >= 0;
      float s = valid ? scales[bix] : 1.0f;
      float t = valid ? shifts[bix] : 0.0f;
      if (n < 10u) { s = 1.0f; t = 0.0f; }
      fbcast[0] = s; fbcast[1] = t;
    }
    __syncthreads();
    float s = fbcast[0], t = fbcast[1];

    double acc = 0.0;
    const float4* d4 = (const float4*)dren;
    const float4* p4 = (const float4*)dpri;
    const int P4 = P >> 2;
    for (int i = gid; i < P4; i += NALL) {
      float4 d = d4[i], p = p4[i];
      float dc[4] = { d.x, d.y, d.z, d.w };
      float pc[4] = { p.x, p.y, p.z, p.w };
#pragma unroll
      for (int k = 0; k < 4; k++) {
        float al = __fadd_rn(__fmul_rn(s, pc[k]), t);
        out_depth[4 * i + k] = __fdiv_rn(1.0f, fmaxf(al, 1e-4f));
        float dv = dc[k];
        if ((dv > 0.1f) && (dv < 100.0f) && isfinite(dv)) {
          float yv = __fdiv_rn(1.0f, __fadd_rn(dv, 1e-6f));
          acc += (double)fabsf(__fsub_rn(al, yv));
        }
      }
    }
    for (int i = (P & ~3) + gid; i < P; i += NALL) {
      float al = __fadd_rn(__fmul_rn(s, dpri[i]), t);
      out_depth[i] = __fdiv_rn(1.0f, fmaxf(al, 1e-4f));
      float dv = dren[i];
      if ((dv > 0.1f) && (dv < 100.0f) && isfinite(dv)) {
        float yv = __fdiv_rn(1.0f, __fadd_rn(dv, 1e-6f));
        acc += (double)fabsf(__fsub_rn(al, yv));
      }
    }
    for (int off = 32; off > 0; off >>= 1) acc += __shfl_down(acc, off);
    if (lane == 0) dred[wid] = acc;
    __syncthreads();
    if (tid == 0) {
      double tot = 0.0;
      for (int w = 0; w < 16; w++) tot += dred[w];
      ((double*)(WS + W_PERLOSS))[bid] = tot;
    }
  }
  gridbar(WS);   // B6

  // ==== block 0: final loss ====
  if (bid == 0) {
    const double* perloss = (const double*)(WS + W_PERLOSS);
    double v = (tid < 256) ? perloss[tid] : 0.0;
    for (int off = 32; off > 0; off >>= 1) v += __shfl_down(v, off);
    if (lane == 0) dred[wid] = v;
    __syncthreads();
    if (tid == 0) {
      double total = 0.0;
      for (int w = 0; w < 16; w++) total += dred[w];
      uint32_t nd = n ? n : 1u;
      float l1 = __fdiv_rn((float)total, (float)nd);
      out[0] = (n < 100u) ? 0.0f : __fmul_rn(0.5f, l1);
    }
  }
}

// ---------------------------------------------------------------------------
extern "C" void kernel_launch(void* const* d_in, const int* in_sizes, int n_in,
                              void* d_out, int out_size, void* d_ws, size_t ws_size,
                              hipStream_t stream) {
  const float* d_ren = (const float*)d_in[0];
  const float* d_pri = (const float*)d_in[1];
  int P = in_sizes[0];
  mega<<<NB, NT, 0, stream>>>(d_ren, d_pri, (float*)d_out, (uint32_t*)d_ws, P);
}

// Round 4
// 522.031 us; speedup vs baseline: 1.6505x; 1.6505x over previous
//
#include <hip/hip_runtime.h>
#include <stdint.h>
#include <math.h>

// ---------------------------------------------------------------------------
// DepthPriorLoss — multi-kernel (7 dispatches), "last-block finalize" style.
// Lesson from rounds 2/3: software grid barriers cost 50-100us each on
// MI355X; hardware dispatch boundaries cost ~6us. So: separate kernels for
// each global sync, and fold every serial step into the last-finishing
// block of the preceding streaming kernel (done-counter + threadfence;
// winner reads cross-block data via agent-scope atomic loads).
// All value-visible math identical to the round-1 passing version
// (threefry partitionable PRNG, exact medians, __f*_rn) -> bit-exact.
// ---------------------------------------------------------------------------

#define NT 256
#define GA 1024   // elemwise + coarse hist 1
#define GB 512    // pairs/subs + collect 1
#define GC 1024   // coarse hist 2
#define GD 512    // collect 2
#define GE 125    // RANSAC (8 candidates per block)
#define GF 1024   // final elemwise
#define LCAP 262144u

// word offsets in WS (uint32 units)
enum : uint32_t {
  W_DONE = 0,          // [6] per-kernel done counters
  W_CNT  = 8,          // [4] list counters A1,B1,A2,B2
  W_N    = 12,
  W_SB1  = 16,         // binA1, rkA1, binB1, rkB1
  W_SB2  = 20,
  W_MED  = 24, W_DYN = 25, W_S = 26, W_T = 27,
  W_LOSS = 28,         // double (byte 112, 8-aligned)
  W_G1   = 32,         // uint32[16384] coarse hist for median(y)
  W_G2   = 16416,      // uint32[16384] coarse hist for median(|y-med|)
  W_ZEND = 32800,      // zero-init everything below this
  W_PERC = 32800,      // uint32[1024] per-block valid counts
  W_SCALES = 33824,    // float[1000]
  W_SHIFTS = 34824,    // float[1000]
  W_COUNTS = 35824,    // int[1000]
  W_XSUB = 36824,      // float[50000]
  W_YSUB = 86824,      // float[50000]
  W_LA1  = 136832,     // uint32[LCAP]
  W_LB1  = W_LA1 + LCAP,
  W_LA2  = W_LB1 + LCAP,
  W_LB2  = W_LA2 + LCAP
};

// ---------------- threefry2x32 (JAX-exact, partitionable mode) -------------
__device__ __forceinline__ uint32_t rotl32(uint32_t v, int d) {
  return (v << d) | (v >> (32 - d));
}
__device__ __forceinline__ void tf2x32(uint32_t k0, uint32_t k1,
                                       uint32_t c0, uint32_t c1,
                                       uint32_t& o0, uint32_t& o1) {
  uint32_t ks2 = k0 ^ k1 ^ 0x1BD11BDAu;
  uint32_t x0 = c0 + k0;
  uint32_t x1 = c1 + k1;
#define TFR(r) { x0 += x1; x1 = rotl32(x1, r); x1 ^= x0; }
  TFR(13) TFR(15) TFR(26) TFR(6)
  x0 += k1;  x1 += ks2 + 1u;
  TFR(17) TFR(29) TFR(16) TFR(24)
  x0 += ks2; x1 += k0 + 2u;
  TFR(13) TFR(15) TFR(26) TFR(6)
  x0 += k0;  x1 += k1 + 3u;
  TFR(17) TFR(29) TFR(16) TFR(24)
  x0 += k1;  x1 += ks2 + 4u;
  TFR(13) TFR(15) TFR(26) TFR(6)
  x0 += ks2; x1 += k0 + 5u;
#undef TFR
  o0 = x0; o1 = x1;
}
struct Keys { uint32_t hp0, hp1, lp0, lp1, hs0, hs1, ls0, ls1; };
__device__ __forceinline__ Keys derive_keys() {
  Keys K; uint32_t p0, p1, q0, q1;
  tf2x32(0u, 42u, 0u, 0u, p0, p1);
  tf2x32(0u, 42u, 0u, 1u, q0, q1);
  tf2x32(p0, p1, 0u, 0u, K.hp0, K.hp1);
  tf2x32(p0, p1, 0u, 1u, K.lp0, K.lp1);
  tf2x32(q0, q1, 0u, 0u, K.hs0, K.hs1);
  tf2x32(q0, q1, 0u, 1u, K.ls0, K.ls1);
  return K;
}
__device__ __forceinline__ uint32_t bits32(uint32_t k0, uint32_t k1, uint32_t e) {
  uint32_t a, b; tf2x32(k0, k1, 0u, e, a, b); return a ^ b;
}
__device__ __forceinline__ uint32_t ri_offset(uint32_t hi, uint32_t lo, uint32_t span) {
  uint32_t m = 65536u % span;
  m = (m * m) % span;
  uint32_t off = (hi % span) * m + (lo % span);
  return off % span;
}

// ---------------- order-preserving float<->uint ----------------------------
__device__ __forceinline__ uint32_t f2u(float f) {
  uint32_t u = __float_as_uint(f);
  return (u & 0x80000000u) ? ~u : (u | 0x80000000u);
}
__device__ __forceinline__ float u2f(uint32_t u) {
  uint32_t v = (u & 0x80000000u) ? (u & 0x7FFFFFFFu) : ~u;
  return __uint_as_float(v);
}
__device__ __forceinline__ uint32_t yval_u(float dv, float& y, bool& m) {
  y = __fdiv_rn(1.0f, __fadd_rn(dv, 1e-6f));
  m = (dv > 0.1f) && (dv < 100.0f) && isfinite(dv);
  return m ? f2u(y) : 0xFFFFFFFFu;
}
__device__ __forceinline__ uint32_t m2w(uint32_t u, float med) {
  return (u != 0xFFFFFFFFu) ? f2u(fabsf(__fsub_rn(u2f(u), med))) : 0xFFFFFFFFu;
}

// ---------------- agent-scope atomic helpers -------------------------------
__device__ __forceinline__ uint32_t aload(const uint32_t* p) {
  return __hip_atomic_load(p, __ATOMIC_RELAXED, __HIP_MEMORY_SCOPE_AGENT);
}
__device__ __forceinline__ void astore(uint32_t* p, uint32_t v) {
  __hip_atomic_store(p, v, __ATOMIC_RELAXED, __HIP_MEMORY_SCOPE_AGENT);
}
__device__ __forceinline__ double aloadd(const double* p) {
  return __hip_atomic_load(p, __ATOMIC_RELAXED, __HIP_MEMORY_SCOPE_AGENT);
}

// last-finishing-block election (no spinning; winner does the serial tail)
__device__ __forceinline__ bool last_block(uint32_t* done, int grid, int* flag) {
  __syncthreads();
  if (threadIdx.x == 0) {
    __threadfence();
    uint32_t old = __hip_atomic_fetch_add(done, 1u, __ATOMIC_ACQ_REL,
                                          __HIP_MEMORY_SCOPE_AGENT);
    *flag = (old == (uint32_t)(grid - 1)) ? 1 : 0;
  }
  __syncthreads();
  return *flag != 0;
}

// ---------------- block reduction / scan (256 threads) ---------------------
__device__ __forceinline__ uint32_t block_sum_u32(uint32_t v, uint32_t* wl) {
  const int lane = threadIdx.x & 63, wid = threadIdx.x >> 6;
  for (int off = 32; off > 0; off >>= 1) v += __shfl_down(v, off);
  __syncthreads();
  if (lane == 0) wl[wid] = v;
  __syncthreads();
  return wl[0] + wl[1] + wl[2] + wl[3];
}
__device__ __forceinline__ uint32_t scan_excl(uint32_t local, uint32_t* wl) {
  const int lane = threadIdx.x & 63, wid = threadIdx.x >> 6;
  __syncthreads();
  uint32_t v = local;
#pragma unroll
  for (int off = 1; off < 64; off <<= 1) {
    uint32_t o = __shfl_up(v, off);
    if (lane >= off) v += o;
  }
  if (lane == 63) wl[wid] = v;
  __syncthreads();
  uint32_t base = 0;
  for (int w = 0; w < 4; w++) if (w < wid) base += wl[w];
  return base + v - local;
}

// dual-rank select over the 16384-bin global hist (winner block only)
__device__ void g_select2(const uint32_t* G, uint32_t rkA, uint32_t rkB,
                          uint32_t* wl, uint32_t* bc4) {
  const int tid = threadIdx.x;
  uint32_t local = 0;
  for (int k = 0; k < 64; k++) local += aload(&G[tid * 64 + k]);
  uint32_t excl = scan_excl(local, wl);
  for (int s = 0; s < 2; s++) {
    uint32_t rk = s ? rkB : rkA;
    if (local > 0 && rk >= excl && rk < excl + local) {
      uint32_t c = excl;
      for (int k = 0; k < 64; k++) {
        uint32_t v = aload(&G[tid * 64 + k]);
        if (rk < c + v) { bc4[2 * s] = (uint32_t)(tid * 64 + k); bc4[2 * s + 1] = rk - c; break; }
        c += v;
      }
    }
  }
  __syncthreads();
}

// exact rank-rk element of a coarse-bin list (winner block only).
// value = ((16384+bin14)<<17) | low17; hist 9 bits then 8 bits.
__device__ uint32_t select17(const uint32_t* L, uint32_t cnt, uint32_t rk,
                             uint32_t bin14, uint32_t* h512, uint32_t* h256,
                             uint32_t* wl, uint32_t* bc) {
  const int tid = threadIdx.x;
  __syncthreads();
  h512[2 * tid] = 0; h512[2 * tid + 1] = 0; h256[tid] = 0;
  __syncthreads();
  for (uint32_t i = tid; i < cnt; i += NT)
    atomicAdd(&h512[(aload(&L[i]) >> 8) & 511u], 1u);
  __syncthreads();
  uint32_t a0 = h512[2 * tid], a1 = h512[2 * tid + 1];
  uint32_t local = a0 + a1;
  uint32_t excl = scan_excl(local, wl);
  if (local > 0 && rk >= excl && rk < excl + local) {
    if (rk < excl + a0) { bc[0] = (uint32_t)(2 * tid); bc[1] = rk - excl; }
    else { bc[0] = (uint32_t)(2 * tid + 1); bc[1] = rk - excl - a0; }
  }
  __syncthreads();
  uint32_t binA = bc[0], rk2 = bc[1];
  __syncthreads();
  for (uint32_t i = tid; i < cnt; i += NT) {
    uint32_t v = aload(&L[i]);
    if (((v >> 8) & 511u) == binA) atomicAdd(&h256[v & 255u], 1u);
  }
  __syncthreads();
  uint32_t l2 = h256[tid];
  uint32_t e2 = scan_excl(l2, wl);
  if (l2 > 0 && rk2 >= e2 && rk2 < e2 + l2) bc[0] = (uint32_t)tid;
  __syncthreads();
  uint32_t binB = bc[0];
  __syncthreads();
  return ((16384u + bin14) << 17) | (binA << 8) | binB;
}

// ---------------- kernels --------------------------------------------------
__global__ void k_zero(uint32_t* WS) {
  int i = blockIdx.x * blockDim.x + threadIdx.x;
  if (i < (int)W_ZEND) WS[i] = 0u;
}

// kA: stream dren -> valid count + coarse hist G1; winner: n + g_select2(G1)
__global__ __launch_bounds__(NT) void kA(const float* __restrict__ dren,
                                         uint32_t* __restrict__ WS, int P) {
  const int tid = threadIdx.x, bid = blockIdx.x, gid = bid * NT + tid;
  __shared__ uint32_t smem[8192];
  __shared__ uint32_t wl[4];
  __shared__ uint32_t bc4[4];
  __shared__ int flag;
  for (int i = tid; i < 8192; i += NT) smem[i] = 0u;
  __syncthreads();
  uint32_t cnt = 0;
  const float4* d4 = (const float4*)dren;
  const int P4 = P >> 2;
  for (int i = gid; i < P4; i += GA * NT) {
    float4 d = d4[i];
    float dc[4] = { d.x, d.y, d.z, d.w };
#pragma unroll
    for (int k = 0; k < 4; k++) {
      float y; bool m;
      uint32_t u = yval_u(dc[k], y, m);
      cnt += m ? 1u : 0u;
      uint32_t bin = (u >> 17) & 16383u;
      atomicAdd(&smem[bin >> 1], 1u << ((bin & 1u) << 4));
    }
  }
  for (int i = (P & ~3) + gid; i < P; i += GA * NT) {
    float y; bool m;
    uint32_t u = yval_u(dren[i], y, m);
    cnt += m ? 1u : 0u;
    uint32_t bin = (u >> 17) & 16383u;
    atomicAdd(&smem[bin >> 1], 1u << ((bin & 1u) << 4));
  }
  uint32_t btot = block_sum_u32(cnt, wl);
  if (tid == 0) astore(&WS[W_PERC + bid], btot);
  __syncthreads();
  for (int w = tid; w < 8192; w += NT) {
    uint32_t pv = smem[w];
    if (pv) {
      uint32_t lo = pv & 0xFFFFu, hi = pv >> 16;
      if (lo) atomicAdd(&WS[W_G1 + 2 * w], lo);
      if (hi) atomicAdd(&WS[W_G1 + 2 * w + 1], hi);
    }
  }
  if (!last_block(&WS[W_DONE + 0], GA, &flag)) return;
  // winner: n, ranks, coarse bins for median(y)
  uint32_t local = 0;
  for (int k = 0; k < 4; k++) local += aload(&WS[W_PERC + tid * 4 + k]);
  uint32_t n = block_sum_u32(local, wl);
  uint32_t nn = n ? n : 1u;
  g_select2(WS + W_G1, (nn - 1u) >> 1, nn >> 1, wl, bc4);
  if (tid == 0) {
    WS[W_N] = n;
    WS[W_SB1 + 0] = bc4[0]; WS[W_SB1 + 1] = bc4[1];
    WS[W_SB1 + 2] = bc4[2]; WS[W_SB1 + 3] = bc4[3];
  }
}

// kB: pairs + subs + collect median-1 lists; winner: med
__global__ __launch_bounds__(NT) void kB(const float* __restrict__ dren,
                                         const float* __restrict__ dpri,
                                         uint32_t* __restrict__ WS, int P) {
  const int tid = threadIdx.x, bid = blockIdx.x, gid = bid * NT + tid;
  __shared__ uint32_t bufA[4096], bufB[4096];
  __shared__ uint32_t cA, cB, baseA, baseB;
  __shared__ uint32_t h512[512], h256[256];
  __shared__ uint32_t wl[4], bc[2];
  __shared__ int flag;
  const uint32_t n = WS[W_N];
  const uint32_t binA1 = WS[W_SB1 + 0], rkA1 = WS[W_SB1 + 1];
  const uint32_t binB1 = WS[W_SB1 + 2], rkB1 = WS[W_SB1 + 3];
  const bool dv1 = (binA1 != binB1);
  if (tid == 0) { cA = 0; cB = 0; }
  __syncthreads();
  // pairs + subs
  {
    uint32_t span = n ? n : 1u;
    if (gid < 1000) {
      Keys K = derive_keys();
      uint32_t hi0 = bits32(K.hp0, K.hp1, (uint32_t)(2 * gid));
      uint32_t lo0 = bits32(K.lp0, K.lp1, (uint32_t)(2 * gid));
      uint32_t hi1 = bits32(K.hp0, K.hp1, (uint32_t)(2 * gid + 1));
      uint32_t lo1 = bits32(K.lp0, K.lp1, (uint32_t)(2 * gid + 1));
      uint32_t i0 = ri_offset(hi0, lo0, span);
      uint32_t i1 = ri_offset(hi1, lo1, span);
      float x1v = dpri[i0], x2v = dpri[i1];
      float y1v = __fdiv_rn(1.0f, __fadd_rn(dren[i0], 1e-6f));
      float y2v = __fdiv_rn(1.0f, __fadd_rn(dren[i1], 1e-6f));
      float sc = __fdiv_rn(__fsub_rn(y2v, y1v),
                           __fadd_rn(__fsub_rn(x2v, x1v), 1e-8f));
      ((float*)WS)[W_SCALES + gid] = sc;
      ((float*)WS)[W_SHIFTS + gid] = __fsub_rn(y1v, __fmul_rn(sc, x1v));
    }
    if (gid < 50000) {
      Keys K = derive_keys();
      uint32_t hi = bits32(K.hs0, K.hs1, (uint32_t)gid);
      uint32_t lo = bits32(K.ls0, K.ls1, (uint32_t)gid);
      uint32_t idx = ri_offset(hi, lo, span);
      ((float*)WS)[W_XSUB + gid] = dpri[idx];
      ((float*)WS)[W_YSUB + gid] = __fdiv_rn(1.0f, __fadd_rn(dren[idx], 1e-6f));
    }
  }
  // collect coarse-bin elements (LDS staged, one global atomic per block)
  const float4* d4 = (const float4*)dren;
  const int P4 = P >> 2;
  for (int i = gid; i < P4; i += GB * NT) {
    float4 d = d4[i];
    float dc[4] = { d.x, d.y, d.z, d.w };
#pragma unroll
    for (int k = 0; k < 4; k++) {
      float y; bool m;
      uint32_t u = yval_u(dc[k], y, m);
      uint32_t b = (u >> 17) & 16383u;
      if (b == binA1) { uint32_t j = atomicAdd(&cA, 1u); if (j < 4096u) bufA[j] = u; }
      else if (dv1 && b == binB1) { uint32_t j = atomicAdd(&cB, 1u); if (j < 4096u) bufB[j] = u; }
    }
  }
  for (int i = (P & ~3) + gid; i < P; i += GB * NT) {
    float y; bool m;
    uint32_t u = yval_u(dren[i], y, m);
    uint32_t b = (u >> 17) & 16383u;
    if (b == binA1) { uint32_t j = atomicAdd(&cA, 1u); if (j < 4096u) bufA[j] = u; }
    else if (dv1 && b == binB1) { uint32_t j = atomicAdd(&cB, 1u); if (j < 4096u) bufB[j] = u; }
  }
  __syncthreads();
  if (tid == 0) {
    uint32_t a = cA > 4096u ? 4096u : cA;
    uint32_t b = cB > 4096u ? 4096u : cB;
    cA = a; cB = b;
    baseA = a ? atomicAdd(&WS[W_CNT + 0], a) : 0u;
    baseB = b ? atomicAdd(&WS[W_CNT + 1], b) : 0u;
  }
  __syncthreads();
  for (uint32_t k = tid; k < cA; k += NT)
    if (baseA + k < LCAP) astore(&WS[W_LA1 + baseA + k], bufA[k]);
  for (uint32_t k = tid; k < cB; k += NT)
    if (baseB + k < LCAP) astore(&WS[W_LB1 + baseB + k], bufB[k]);
  if (!last_block(&WS[W_DONE + 1], GB, &flag)) return;
  // winner: exact median(y)
  uint32_t cA1 = aload(&WS[W_CNT + 0]); if (cA1 > LCAP) cA1 = LCAP;
  uint32_t vA = select17(WS + W_LA1, cA1, rkA1, binA1, h512, h256, wl, bc);
  uint32_t vB;
  if (dv1) {
    uint32_t cB1 = aload(&WS[W_CNT + 1]); if (cB1 > LCAP) cB1 = LCAP;
    vB = select17(WS + W_LB1, cB1, rkB1, binB1, h512, h256, wl, bc);
  } else {
    vB = select17(WS + W_LA1, cA1, rkB1, binA1, h512, h256, wl, bc);
  }
  if (tid == 0)
    ((float*)WS)[W_MED] = __fmul_rn(__fadd_rn(u2f(vA), u2f(vB)), 0.5f);
}

// kC: coarse hist of |y - med|; winner: g_select2(G2)
__global__ __launch_bounds__(NT) void kC(const float* __restrict__ dren,
                                         uint32_t* __restrict__ WS, int P) {
  const int tid = threadIdx.x, bid = blockIdx.x, gid = bid * NT + tid;
  __shared__ uint32_t smem[8192];
  __shared__ uint32_t wl[4];
  __shared__ uint32_t bc4[4];
  __shared__ int flag;
  const float med = ((const float*)WS)[W_MED];
  for (int i = tid; i < 8192; i += NT) smem[i] = 0u;
  __syncthreads();
  const float4* d4 = (const float4*)dren;
  const int P4 = P >> 2;
  for (int i = gid; i < P4; i += GC * NT) {
    float4 d = d4[i];
    float dc[4] = { d.x, d.y, d.z, d.w };
#pragma unroll
    for (int k = 0; k < 4; k++) {
      float y; bool m;
      uint32_t w = m2w(yval_u(dc[k], y, m), med);
      uint32_t bin = (w >> 17) & 16383u;
      atomicAdd(&smem[bin >> 1], 1u << ((bin & 1u) << 4));
    }
  }
  for (int i = (P & ~3) + gid; i < P; i += GC * NT) {
    float y; bool m;
    uint32_t w = m2w(yval_u(dren[i], y, m), med);
    uint32_t bin = (w >> 17) & 16383u;
    atomicAdd(&smem[bin >> 1], 1u << ((bin & 1u) << 4));
  }
  __syncthreads();
  for (int w = tid; w < 8192; w += NT) {
    uint32_t pv = smem[w];
    if (pv) {
      uint32_t lo = pv & 0xFFFFu, hi = pv >> 16;
      if (lo) atomicAdd(&WS[W_G2 + 2 * w], lo);
      if (hi) atomicAdd(&WS[W_G2 + 2 * w + 1], hi);
    }
  }
  if (!last_block(&WS[W_DONE + 2], GC, &flag)) return;
  uint32_t n = WS[W_N];
  uint32_t nn = n ? n : 1u;
  g_select2(WS + W_G2, (nn - 1u) >> 1, nn >> 1, wl, bc4);
  if (tid == 0) {
    WS[W_SB2 + 0] = bc4[0]; WS[W_SB2 + 1] = bc4[1];
    WS[W_SB2 + 2] = bc4[2]; WS[W_SB2 + 3] = bc4[3];
  }
}

// kD: collect median-2 lists; winner: dyn
__global__ __launch_bounds__(NT) void kD(const float* __restrict__ dren,
                                         uint32_t* __restrict__ WS, int P) {
  const int tid = threadIdx.x, bid = blockIdx.x, gid = bid * NT + tid;
  __shared__ uint32_t bufA[4096], bufB[4096];
  __shared__ uint32_t cA, cB, baseA, baseB;
  __shared__ uint32_t h512[512], h256[256];
  __shared__ uint32_t wl[4], bc[2];
  __shared__ int flag;
  const float med = ((const float*)WS)[W_MED];
  const uint32_t binA2 = WS[W_SB2 + 0], rkA2 = WS[W_SB2 + 1];
  const uint32_t binB2 = WS[W_SB2 + 2], rkB2 = WS[W_SB2 + 3];
  const bool dv2 = (binA2 != binB2);
  if (tid == 0) { cA = 0; cB = 0; }
  __syncthreads();
  const float4* d4 = (const float4*)dren;
  const int P4 = P >> 2;
  for (int i = gid; i < P4; i += GD * NT) {
    float4 d = d4[i];
    float dc[4] = { d.x, d.y, d.z, d.w };
#pragma unroll
    for (int k = 0; k < 4; k++) {
      float y; bool m;
      uint32_t w = m2w(yval_u(dc[k], y, m), med);
      uint32_t b = (w >> 17) & 16383u;
      if (b == binA2) { uint32_t j = atomicAdd(&cA, 1u); if (j < 4096u) bufA[j] = w; }
      else if (dv2 && b == binB2) { uint32_t j = atomicAdd(&cB, 1u); if (j < 4096u) bufB[j] = w; }
    }
  }
  for (int i = (P & ~3) + gid; i < P; i += GD * NT) {
    float y; bool m;
    uint32_t w = m2w(yval_u(dren[i], y, m), med);
    uint32_t b = (w >> 17) & 16383u;
    if (b == binA2) { uint32_t j = atomicAdd(&cA, 1u); if (j < 4096u) bufA[j] = w; }
    else if (dv2 && b == binB2) { uint32_t j = atomicAdd(&cB, 1u); if (j < 4096u) bufB[j] = w; }
  }
  __syncthreads();
  if (tid == 0) {
    uint32_t a = cA > 4096u ? 4096u : cA;
    uint32_t b = cB > 4096u ? 4096u : cB;
    cA = a; cB = b;
    baseA = a ? atomicAdd(&WS[W_CNT + 2], a) : 0u;
    baseB = b ? atomicAdd(&WS[W_CNT + 3], b) : 0u;
  }
  __syncthreads();
  for (uint32_t k = tid; k < cA; k += NT)
    if (baseA + k < LCAP) astore(&WS[W_LA2 + baseA + k], bufA[k]);
  for (uint32_t k = tid; k < cB; k += NT)
    if (baseB + k < LCAP) astore(&WS[W_LB2 + baseB + k], bufB[k]);
  if (!last_block(&WS[W_DONE + 3], GD, &flag)) return;
  uint32_t cA2 = aload(&WS[W_CNT + 2]); if (cA2 > LCAP) cA2 = LCAP;
  uint32_t wA = select17(WS + W_LA2, cA2, rkA2, binA2, h512, h256, wl, bc);
  uint32_t wB;
  if (dv2) {
    uint32_t cB2 = aload(&WS[W_CNT + 3]); if (cB2 > LCAP) cB2 = LCAP;
    wB = select17(WS + W_LB2, cB2, rkB2, binB2, h512, h256, wl, bc);
  } else {
    wB = select17(WS + W_LA2, cA2, rkB2, binA2, h512, h256, wl, bc);
  }
  if (tid == 0) {
    float mad = __fmul_rn(__fadd_rn(u2f(wA), u2f(wB)), 0.5f);
    float dyn = __fmul_rn(mad, 0.5f);
    if (dyn < 1e-5f) dyn = 0.01f;   // THRESH
    ((float*)WS)[W_DYN] = dyn;
  }
}

// kE: RANSAC scoring (8 candidates/block); winner: argmax -> s,t
__global__ __launch_bounds__(NT) void kE(uint32_t* __restrict__ WS) {
  const int tid = threadIdx.x, bid = blockIdx.x;
  const int lane = tid & 63, wid = tid >> 6;
  __shared__ int ired[32];
  __shared__ int iidx[4];
  __shared__ int flag;
  const float dyn = ((const float*)WS)[W_DYN];
  const float* scales = (const float*)WS + W_SCALES;
  const float* shifts = (const float*)WS + W_SHIFTS;
  const float* x_sub  = (const float*)WS + W_XSUB;
  const float* y_sub  = (const float*)WS + W_YSUB;
  const int cbase = bid * 8;
  float ss[8], tt[8]; int c[8];
#pragma unroll
  for (int j = 0; j < 8; j++) { ss[j] = scales[cbase + j]; tt[j] = shifts[cbase + j]; c[j] = 0; }
  for (int e = tid; e < 50000; e += NT) {
    float xe = x_sub[e], ye = y_sub[e];
#pragma unroll
    for (int j = 0; j < 8; j++) {
      float r = fabsf(__fsub_rn(__fadd_rn(__fmul_rn(ss[j], xe), tt[j]), ye));
      c[j] += (r < dyn) ? 1 : 0;
    }
  }
#pragma unroll
  for (int j = 0; j < 8; j++) {
    int v = c[j];
    for (int off = 32; off > 0; off >>= 1) v += __shfl_down(v, off);
    if (lane == 0) ired[wid * 8 + j] = v;
  }
  __syncthreads();
  if (tid < 8) {
    int tot = ired[tid] + ired[8 + tid] + ired[16 + tid] + ired[24 + tid];
    int cv = (ss[tid] > 0.0f) ? tot : -1;
    astore(&WS[W_COUNTS + cbase + tid], (uint32_t)cv);
  }
  if (!last_block(&WS[W_DONE + 4], GE, &flag)) return;
  // winner: argmax (first occurrence of max)
  int bcn = -2, bix = 0x7FFFFFFF;
  for (int j = tid; j < 1000; j += NT) {
    int cc = (int)aload(&WS[W_COUNTS + j]);
    if (cc > bcn) { bcn = cc; bix = j; }
  }
  for (int off = 32; off > 0; off >>= 1) {
    int oc = __shfl_down(bcn, off), oi = __shfl_down(bix, off);
    if (oc > bcn || (oc == bcn && oi < bix)) { bcn = oc; bix = oi; }
  }
  if (lane == 0) { ired[wid] = bcn; iidx[wid] = bix; }
  __syncthreads();
  if (tid == 0) {
    for (int w = 1; w < 4; w++) {
      if (ired[w] > ired[0] || (ired[w] == ired[0] && iidx[w] < iidx[0])) {
        ired[0] = ired[w]; iidx[0] = iidx[w];
      }
    }
    bool valid = ired[0] >= 0;
    float s = valid ? scales[iidx[0]] : 1.0f;
    float t = valid ? shifts[iidx[0]] : 0.0f;
    uint32_t n = WS[W_N];
    if (n < 10u) { s = 1.0f; t = 0.0f; }
    ((float*)WS)[W_S] = s;
    ((float*)WS)[W_T] = t;
  }
}

// kF: final elemwise (out_y, out_depth, masked L1 partial); winner: out[0]
__global__ __launch_bounds__(NT) void kF(const float* __restrict__ dren,
                                         const float* __restrict__ dpri,
                                         float* __restrict__ out,
                                         uint32_t* __restrict__ WS, int P) {
  const int tid = threadIdx.x, bid = blockIdx.x, gid = bid * NT + tid;
  const int lane = tid & 63, wid = tid >> 6;
  __shared__ double dred[4];
  __shared__ int flag;
  const float s = ((const float*)WS)[W_S];
  const float t = ((const float*)WS)[W_T];
  float* out_y = out + 1;
  float* out_depth = out + 1 + P;
  double acc = 0.0;
  const float4* d4 = (const float4*)dren;
  const float4* p4 = (const float4*)dpri;
  const int P4 = P >> 2;
  for (int i = gid; i < P4; i += GF * NT) {
    float4 d = d4[i], p = p4[i];
    float dc[4] = { d.x, d.y, d.z, d.w };
    float pc[4] = { p.x, p.y, p.z, p.w };
#pragma unroll
    for (int k = 0; k < 4; k++) {
      float yv = __fdiv_rn(1.0f, __fadd_rn(dc[k], 1e-6f));
      out_y[4 * i + k] = yv;
      float al = __fadd_rn(__fmul_rn(s, pc[k]), t);
      out_depth[4 * i + k] = __fdiv_rn(1.0f, fmaxf(al, 1e-4f));
      bool m = (dc[k] > 0.1f) && (dc[k] < 100.0f) && isfinite(dc[k]);
      if (m) acc += (double)fabsf(__fsub_rn(al, yv));
    }
  }
  for (int i = (P & ~3) + gid; i < P; i += GF * NT) {
    float dv = dren[i];
    float yv = __fdiv_rn(1.0f, __fadd_rn(dv, 1e-6f));
    out_y[i] = yv;
    float al = __fadd_rn(__fmul_rn(s, dpri[i]), t);
    out_depth[i] = __fdiv_rn(1.0f, fmaxf(al, 1e-4f));
    bool m = (dv > 0.1f) && (dv < 100.0f) && isfinite(dv);
    if (m) acc += (double)fabsf(__fsub_rn(al, yv));
  }
  for (int off = 32; off > 0; off >>= 1) acc += __shfl_down(acc, off);
  __syncthreads();
  if (lane == 0) dred[wid] = acc;
  __syncthreads();
  if (tid == 0)
    atomicAdd((double*)(WS + W_LOSS), dred[0] + dred[1] + dred[2] + dred[3]);
  if (!last_block(&WS[W_DONE + 5], GF, &flag)) return;
  if (tid == 0) {
    double total = aloadd((const double*)(WS + W_LOSS));
    uint32_t n = WS[W_N];
    uint32_t nd = n ? n : 1u;
    float l1 = __fdiv_rn((float)total, (float)nd);
    out[0] = (n < 100u) ? 0.0f : __fmul_rn(0.5f, l1);
  }
}

// ---------------------------------------------------------------------------
extern "C" void kernel_launch(void* const* d_in, const int* in_sizes, int n_in,
                              void* d_out, int out_size, void* d_ws, size_t ws_size,
                              hipStream_t stream) {
  const float* d_ren = (const float*)d_in[0];
  const float* d_pri = (const float*)d_in[1];
  float* out = (float*)d_out;
  uint32_t* WS = (uint32_t*)d_ws;
  int P = in_sizes[0];

  k_zero<<<(W_ZEND + NT - 1) / NT, NT, 0, stream>>>(WS);
  kA<<<GA, NT, 0, stream>>>(d_ren, WS, P);
  kB<<<GB, NT, 0, stream>>>(d_ren, d_pri, WS, P);
  kC<<<GC, NT, 0, stream>>>(d_ren, WS, P);
  kD<<<GD, NT, 0, stream>>>(d_ren, WS, P);
  kE<<<GE, NT, 0, stream>>>(WS);
  kF<<<GF, NT, 0, stream>>>(d_ren, d_pri, out, WS, P);
}

// Round 5
// 352.524 us; speedup vs baseline: 2.4441x; 1.4808x over previous
//
#include <hip/hip_runtime.h>
#include <stdint.h>
#include <math.h>

// ---------------------------------------------------------------------------
// DepthPriorLoss — 8 dispatches, NO in-kernel cross-block sync.
// Round-4 lesson: agent-scope fences/RMWs on gfx950 emit per-XCD L2
// writeback/invalidate (buffer_wbl2/buffer_inv); one per block is a 10x
// slowdown. Dispatch boundaries are coherent and cost ~4us (round 1).
// So: serial glue steps are REDUNDANTLY recomputed per block from
// previous-dispatch data; scalars are published via identical-value plain
// stores. All value-visible math identical to the passing round-1 code.
// ---------------------------------------------------------------------------

#define NT 256
#define GA 1024   // hist1 + valid count
#define GB 512    // bins1 + pairs/subs + collect1
#define GC 1024   // med + hist2
#define GD 512    // bins2 + collect2
#define GE 250    // dyn + RANSAC (4 candidates/block)
#define GF 1024   // argmax + final elemwise
#define LCAP 262144u

// word offsets in WS
enum : uint32_t {
  W_CNT  = 0,          // [4] list counters A1,B1,A2,B2
  W_LOSS = 4,          // [2] double (byte 16, 8-aligned)
  W_N    = 6,
  W_MED  = 7,
  W_SB1  = 8,          // binA1, rkA1, binB1, rkB1
  W_SB2  = 12,
  W_G1   = 16,         // uint32[16384]
  W_G2   = 16400,      // uint32[16384]
  W_ZEND = 32784,
  W_PERC = 32784,      // uint32[1024]
  W_SCALES = 33808,    // float[1000]
  W_SHIFTS = 34808,    // float[1000]
  W_COUNTS = 35808,    // int[1000]
  W_XSUB = 36808,      // float[50000]
  W_YSUB = 86808,      // float[50000]
  W_LA1  = 136832,     // uint32[LCAP] x 4
  W_LB1  = W_LA1 + LCAP,
  W_LA2  = W_LB1 + LCAP,
  W_LB2  = W_LA2 + LCAP
};

// ---------------- threefry2x32 (JAX-exact, partitionable mode) -------------
__device__ __forceinline__ uint32_t rotl32(uint32_t v, int d) {
  return (v << d) | (v >> (32 - d));
}
__device__ __forceinline__ void tf2x32(uint32_t k0, uint32_t k1,
                                       uint32_t c0, uint32_t c1,
                                       uint32_t& o0, uint32_t& o1) {
  uint32_t ks2 = k0 ^ k1 ^ 0x1BD11BDAu;
  uint32_t x0 = c0 + k0;
  uint32_t x1 = c1 + k1;
#define TFR(r) { x0 += x1; x1 = rotl32(x1, r); x1 ^= x0; }
  TFR(13) TFR(15) TFR(26) TFR(6)
  x0 += k1;  x1 += ks2 + 1u;
  TFR(17) TFR(29) TFR(16) TFR(24)
  x0 += ks2; x1 += k0 + 2u;
  TFR(13) TFR(15) TFR(26) TFR(6)
  x0 += k0;  x1 += k1 + 3u;
  TFR(17) TFR(29) TFR(16) TFR(24)
  x0 += k1;  x1 += ks2 + 4u;
  TFR(13) TFR(15) TFR(26) TFR(6)
  x0 += ks2; x1 += k0 + 5u;
#undef TFR
  o0 = x0; o1 = x1;
}
struct Keys { uint32_t hp0, hp1, lp0, lp1, hs0, hs1, ls0, ls1; };
__device__ __forceinline__ Keys derive_keys() {
  Keys K; uint32_t p0, p1, q0, q1;
  tf2x32(0u, 42u, 0u, 0u, p0, p1);
  tf2x32(0u, 42u, 0u, 1u, q0, q1);
  tf2x32(p0, p1, 0u, 0u, K.hp0, K.hp1);
  tf2x32(p0, p1, 0u, 1u, K.lp0, K.lp1);
  tf2x32(q0, q1, 0u, 0u, K.hs0, K.hs1);
  tf2x32(q0, q1, 0u, 1u, K.ls0, K.ls1);
  return K;
}
__device__ __forceinline__ uint32_t bits32(uint32_t k0, uint32_t k1, uint32_t e) {
  uint32_t a, b; tf2x32(k0, k1, 0u, e, a, b); return a ^ b;
}
__device__ __forceinline__ uint32_t ri_offset(uint32_t hi, uint32_t lo, uint32_t span) {
  uint32_t m = 65536u % span;
  m = (m * m) % span;
  uint32_t off = (hi % span) * m + (lo % span);
  return off % span;
}

// ---------------- order-preserving float<->uint ----------------------------
__device__ __forceinline__ uint32_t f2u(float f) {
  uint32_t u = __float_as_uint(f);
  return (u & 0x80000000u) ? ~u : (u | 0x80000000u);
}
__device__ __forceinline__ float u2f(uint32_t u) {
  uint32_t v = (u & 0x80000000u) ? (u & 0x7FFFFFFFu) : ~u;
  return __uint_as_float(v);
}
__device__ __forceinline__ uint32_t yval_u(float dv, float& y, bool& m) {
  y = __fdiv_rn(1.0f, __fadd_rn(dv, 1e-6f));
  m = (dv > 0.1f) && (dv < 100.0f) && isfinite(dv);
  return m ? f2u(y) : 0xFFFFFFFFu;
}
__device__ __forceinline__ uint32_t m2w(uint32_t u, float med) {
  return (u != 0xFFFFFFFFu) ? f2u(fabsf(__fsub_rn(u2f(u), med))) : 0xFFFFFFFFu;
}

// ---------------- block reduction / scan (256 threads) ---------------------
__device__ __forceinline__ uint32_t block_sum_u32(uint32_t v, uint32_t* wl) {
  const int lane = threadIdx.x & 63, wid = threadIdx.x >> 6;
  for (int off = 32; off > 0; off >>= 1) v += __shfl_down(v, off);
  __syncthreads();
  if (lane == 0) wl[wid] = v;
  __syncthreads();
  return wl[0] + wl[1] + wl[2] + wl[3];
}
__device__ __forceinline__ uint32_t scan_excl(uint32_t local, uint32_t* wl) {
  const int lane = threadIdx.x & 63, wid = threadIdx.x >> 6;
  __syncthreads();
  uint32_t v = local;
#pragma unroll
  for (int off = 1; off < 64; off <<= 1) {
    uint32_t o = __shfl_up(v, off);
    if (lane >= off) v += o;
  }
  if (lane == 63) wl[wid] = v;
  __syncthreads();
  uint32_t base = 0;
  for (int w = 0; w < 4; w++) if (w < wid) base += wl[w];
  return base + v - local;
}

// dual-rank select over a 16384-bin global hist (per-block redundant, plain loads)
__device__ void g_select2(const uint32_t* __restrict__ G, uint32_t rkA, uint32_t rkB,
                          uint32_t* wl, uint32_t* bc4) {
  const int tid = threadIdx.x;
  if (tid < 4) bc4[tid] = 0u;
  __syncthreads();
  uint32_t local = 0;
  for (int k = 0; k < 64; k++) local += G[tid * 64 + k];
  uint32_t excl = scan_excl(local, wl);
  for (int s = 0; s < 2; s++) {
    uint32_t rk = s ? rkB : rkA;
    if (local > 0 && rk >= excl && rk < excl + local) {
      uint32_t c = excl;
      for (int k = 0; k < 64; k++) {
        uint32_t v = G[tid * 64 + k];
        if (rk < c + v) { bc4[2 * s] = (uint32_t)(tid * 64 + k); bc4[2 * s + 1] = rk - c; break; }
        c += v;
      }
    }
  }
  __syncthreads();
}

// exact rank-rk element of a coarse-bin list (per-block redundant, plain loads)
// value = ((16384+bin14)<<17) | (binA<<8) | binB
__device__ uint32_t select17(const uint32_t* __restrict__ L, uint32_t cnt,
                             uint32_t rk, uint32_t bin14,
                             uint32_t* h512, uint32_t* h256,
                             uint32_t* wl, uint32_t* bc) {
  const int tid = threadIdx.x;
  __syncthreads();
  h512[2 * tid] = 0; h512[2 * tid + 1] = 0; h256[tid] = 0;
  if (tid < 2) bc[tid] = 0u;
  __syncthreads();
  for (uint32_t i = tid; i < cnt; i += NT)
    atomicAdd(&h512[(L[i] >> 8) & 511u], 1u);
  __syncthreads();
  uint32_t a0 = h512[2 * tid], a1 = h512[2 * tid + 1];
  uint32_t local = a0 + a1;
  uint32_t excl = scan_excl(local, wl);
  if (local > 0 && rk >= excl && rk < excl + local) {
    if (rk < excl + a0) { bc[0] = (uint32_t)(2 * tid); bc[1] = rk - excl; }
    else { bc[0] = (uint32_t)(2 * tid + 1); bc[1] = rk - excl - a0; }
  }
  __syncthreads();
  uint32_t binA = bc[0], rk2 = bc[1];
  __syncthreads();
  for (uint32_t i = tid; i < cnt; i += NT) {
    uint32_t v = L[i];
    if (((v >> 8) & 511u) == binA) atomicAdd(&h256[v & 255u], 1u);
  }
  __syncthreads();
  uint32_t l2 = h256[tid];
  uint32_t e2 = scan_excl(l2, wl);
  if (l2 > 0 && rk2 >= e2 && rk2 < e2 + l2) bc[0] = (uint32_t)tid;
  __syncthreads();
  uint32_t binB = bc[0];
  __syncthreads();
  return ((16384u + bin14) << 17) | (binA << 8) | binB;
}

// ---------------- kernels --------------------------------------------------
__global__ void k_zero(uint32_t* WS) {
  int i = blockIdx.x * blockDim.x + threadIdx.x;
  if (i < (int)W_ZEND) WS[i] = 0u;
}

// kA: stream dren -> valid count (W_PERC) + coarse hist G1 (packed-u16 LDS)
__global__ __launch_bounds__(NT) void kA(const float* __restrict__ dren,
                                         uint32_t* __restrict__ WS, int P) {
  const int tid = threadIdx.x, bid = blockIdx.x, gid = bid * NT + tid;
  __shared__ uint32_t lh[8192];
  __shared__ uint32_t wl[4];
  for (int i = tid; i < 8192; i += NT) lh[i] = 0u;
  __syncthreads();
  uint32_t cnt = 0;
  const float4* d4 = (const float4*)dren;
  const int P4 = P >> 2;
  for (int i = gid; i < P4; i += GA * NT) {
    float4 d = d4[i];
    float dc[4] = { d.x, d.y, d.z, d.w };
#pragma unroll
    for (int k = 0; k < 4; k++) {
      float y; bool m;
      uint32_t u = yval_u(dc[k], y, m);
      cnt += m ? 1u : 0u;
      uint32_t bin = (u >> 17) & 16383u;
      atomicAdd(&lh[bin >> 1], 1u << ((bin & 1u) << 4));
    }
  }
  for (int i = (P & ~3) + gid; i < P; i += GA * NT) {
    float y; bool m;
    uint32_t u = yval_u(dren[i], y, m);
    cnt += m ? 1u : 0u;
    uint32_t bin = (u >> 17) & 16383u;
    atomicAdd(&lh[bin >> 1], 1u << ((bin & 1u) << 4));
  }
  uint32_t btot = block_sum_u32(cnt, wl);
  if (tid == 0) WS[W_PERC + bid] = btot;
  __syncthreads();
  for (int w = tid; w < 8192; w += NT) {
    uint32_t pv = lh[w];
    if (pv) {
      uint32_t lo = pv & 0xFFFFu, hi = pv >> 16;
      if (lo) atomicAdd(&WS[W_G1 + 2 * w], lo);
      if (hi) atomicAdd(&WS[W_G1 + 2 * w + 1], hi);
    }
  }
}

// kB: redundant n + bins1; pairs + subs; collect median-1 lists
__global__ __launch_bounds__(NT) void kB(const float* __restrict__ dren,
                                         const float* __restrict__ dpri,
                                         uint32_t* __restrict__ WS, int P) {
  const int tid = threadIdx.x, bid = blockIdx.x, gid = bid * NT + tid;
  __shared__ uint32_t bufA[4096], bufB[4096];
  __shared__ uint32_t cA, cB, baseA, baseB;
  __shared__ uint32_t wl[4], bc4[4];
  // redundant n
  uint32_t local = 0;
#pragma unroll
  for (int k = 0; k < 4; k++) local += WS[W_PERC + tid * 4 + k];
  const uint32_t n = block_sum_u32(local, wl);
  const uint32_t nn = n ? n : 1u;
  // redundant coarse bins for median(y)
  g_select2(WS + W_G1, (nn - 1u) >> 1, nn >> 1, wl, bc4);
  const uint32_t binA1 = bc4[0], binB1 = bc4[2];
  const bool dv1 = (binA1 != binB1);
  if (tid == 0) {   // identical-value stores from every block: benign race
    WS[W_N] = n;
    WS[W_SB1 + 0] = bc4[0]; WS[W_SB1 + 1] = bc4[1];
    WS[W_SB1 + 2] = bc4[2]; WS[W_SB1 + 3] = bc4[3];
    cA = 0; cB = 0;
  }
  __syncthreads();
  // pairs + subs
  {
    uint32_t span = n ? n : 1u;
    if (gid < 1000) {
      Keys K = derive_keys();
      uint32_t hi0 = bits32(K.hp0, K.hp1, (uint32_t)(2 * gid));
      uint32_t lo0 = bits32(K.lp0, K.lp1, (uint32_t)(2 * gid));
      uint32_t hi1 = bits32(K.hp0, K.hp1, (uint32_t)(2 * gid + 1));
      uint32_t lo1 = bits32(K.lp0, K.lp1, (uint32_t)(2 * gid + 1));
      uint32_t i0 = ri_offset(hi0, lo0, span);
      uint32_t i1 = ri_offset(hi1, lo1, span);
      float x1v = dpri[i0], x2v = dpri[i1];
      float y1v = __fdiv_rn(1.0f, __fadd_rn(dren[i0], 1e-6f));
      float y2v = __fdiv_rn(1.0f, __fadd_rn(dren[i1], 1e-6f));
      float sc = __fdiv_rn(__fsub_rn(y2v, y1v),
                           __fadd_rn(__fsub_rn(x2v, x1v), 1e-8f));
      ((float*)WS)[W_SCALES + gid] = sc;
      ((float*)WS)[W_SHIFTS + gid] = __fsub_rn(y1v, __fmul_rn(sc, x1v));
    }
    if (gid < 50000) {
      Keys K = derive_keys();
      uint32_t hi = bits32(K.hs0, K.hs1, (uint32_t)gid);
      uint32_t lo = bits32(K.ls0, K.ls1, (uint32_t)gid);
      uint32_t idx = ri_offset(hi, lo, span);
      ((float*)WS)[W_XSUB + gid] = dpri[idx];
      ((float*)WS)[W_YSUB + gid] = __fdiv_rn(1.0f, __fadd_rn(dren[idx], 1e-6f));
    }
  }
  // collect coarse-bin elements (LDS staged, one global atomicAdd per list)
  const float4* d4 = (const float4*)dren;
  const int P4 = P >> 2;
  for (int i = gid; i < P4; i += GB * NT) {
    float4 d = d4[i];
    float dc[4] = { d.x, d.y, d.z, d.w };
#pragma unroll
    for (int k = 0; k < 4; k++) {
      float y; bool m;
      uint32_t u = yval_u(dc[k], y, m);
      uint32_t b = (u >> 17) & 16383u;
      if (b == binA1) { uint32_t j = atomicAdd(&cA, 1u); if (j < 4096u) bufA[j] = u; }
      else if (dv1 && b == binB1) { uint32_t j = atomicAdd(&cB, 1u); if (j < 4096u) bufB[j] = u; }
    }
  }
  for (int i = (P & ~3) + gid; i < P; i += GB * NT) {
    float y; bool m;
    uint32_t u = yval_u(dren[i], y, m);
    uint32_t b = (u >> 17) & 16383u;
    if (b == binA1) { uint32_t j = atomicAdd(&cA, 1u); if (j < 4096u) bufA[j] = u; }
    else if (dv1 && b == binB1) { uint32_t j = atomicAdd(&cB, 1u); if (j < 4096u) bufB[j] = u; }
  }
  __syncthreads();
  if (tid == 0) {
    uint32_t a = cA > 4096u ? 4096u : cA;
    uint32_t b = cB > 4096u ? 4096u : cB;
    cA = a; cB = b;
    baseA = a ? atomicAdd(&WS[W_CNT + 0], a) : 0u;
    baseB = b ? atomicAdd(&WS[W_CNT + 1], b) : 0u;
  }
  __syncthreads();
  for (uint32_t k = tid; k < cA; k += NT)
    if (baseA + k < LCAP) WS[W_LA1 + baseA + k] = bufA[k];
  for (uint32_t k = tid; k < cB; k += NT)
    if (baseB + k < LCAP) WS[W_LB1 + baseB + k] = bufB[k];
}

// kC: redundant exact median(y); stream hist of |y-med| -> G2
__global__ __launch_bounds__(NT) void kC(const float* __restrict__ dren,
                                         uint32_t* __restrict__ WS, int P) {
  const int tid = threadIdx.x, bid = blockIdx.x, gid = bid * NT + tid;
  __shared__ uint32_t lh[8192];
  __shared__ uint32_t h512[512], h256[256];
  __shared__ uint32_t wl[4], bc[2];
  const uint32_t binA1 = WS[W_SB1 + 0], rkA1 = WS[W_SB1 + 1];
  const uint32_t binB1 = WS[W_SB1 + 2], rkB1 = WS[W_SB1 + 3];
  const bool dv1 = (binA1 != binB1);
  uint32_t cA1 = WS[W_CNT + 0]; if (cA1 > LCAP) cA1 = LCAP;
  uint32_t vA = select17(WS + W_LA1, cA1, rkA1, binA1, h512, h256, wl, bc);
  uint32_t vB;
  if (dv1) {
    uint32_t cB1 = WS[W_CNT + 1]; if (cB1 > LCAP) cB1 = LCAP;
    vB = select17(WS + W_LB1, cB1, rkB1, binB1, h512, h256, wl, bc);
  } else {
    vB = select17(WS + W_LA1, cA1, rkB1, binA1, h512, h256, wl, bc);
  }
  const float med = __fmul_rn(__fadd_rn(u2f(vA), u2f(vB)), 0.5f);
  if (tid == 0) ((float*)WS)[W_MED] = med;   // identical across blocks
  // hist of |y - med|
  __syncthreads();
  for (int i = tid; i < 8192; i += NT) lh[i] = 0u;
  __syncthreads();
  const float4* d4 = (const float4*)dren;
  const int P4 = P >> 2;
  for (int i = gid; i < P4; i += GC * NT) {
    float4 d = d4[i];
    float dc[4] = { d.x, d.y, d.z, d.w };
#pragma unroll
    for (int k = 0; k < 4; k++) {
      float y; bool m;
      uint32_t w = m2w(yval_u(dc[k], y, m), med);
      uint32_t bin = (w >> 17) & 16383u;
      atomicAdd(&lh[bin >> 1], 1u << ((bin & 1u) << 4));
    }
  }
  for (int i = (P & ~3) + gid; i < P; i += GC * NT) {
    float y; bool m;
    uint32_t w = m2w(yval_u(dren[i], y, m), med);
    uint32_t bin = (w >> 17) & 16383u;
    atomicAdd(&lh[bin >> 1], 1u << ((bin & 1u) << 4));
  }
  __syncthreads();
  for (int w = tid; w < 8192; w += NT) {
    uint32_t pv = lh[w];
    if (pv) {
      uint32_t lo = pv & 0xFFFFu, hi = pv >> 16;
      if (lo) atomicAdd(&WS[W_G2 + 2 * w], lo);
      if (hi) atomicAdd(&WS[W_G2 + 2 * w + 1], hi);
    }
  }
}

// kD: redundant bins2 from G2; collect median-2 lists
__global__ __launch_bounds__(NT) void kD(const float* __restrict__ dren,
                                         uint32_t* __restrict__ WS, int P) {
  const int tid = threadIdx.x, bid = blockIdx.x, gid = bid * NT + tid;
  __shared__ uint32_t bufA[4096], bufB[4096];
  __shared__ uint32_t cA, cB, baseA, baseB;
  __shared__ uint32_t wl[4], bc4[4];
  const float med = ((const float*)WS)[W_MED];
  const uint32_t n = WS[W_N];
  const uint32_t nn = n ? n : 1u;
  g_select2(WS + W_G2, (nn - 1u) >> 1, nn >> 1, wl, bc4);
  const uint32_t binA2 = bc4[0], binB2 = bc4[2];
  const bool dv2 = (binA2 != binB2);
  if (tid == 0) {
    WS[W_SB2 + 0] = bc4[0]; WS[W_SB2 + 1] = bc4[1];
    WS[W_SB2 + 2] = bc4[2]; WS[W_SB2 + 3] = bc4[3];
    cA = 0; cB = 0;
  }
  __syncthreads();
  const float4* d4 = (const float4*)dren;
  const int P4 = P >> 2;
  for (int i = gid; i < P4; i += GD * NT) {
    float4 d = d4[i];
    float dc[4] = { d.x, d.y, d.z, d.w };
#pragma unroll
    for (int k = 0; k < 4; k++) {
      float y; bool m;
      uint32_t w = m2w(yval_u(dc[k], y, m), med);
      uint32_t b = (w >> 17) & 16383u;
      if (b == binA2) { uint32_t j = atomicAdd(&cA, 1u); if (j < 4096u) bufA[j] = w; }
      else if (dv2 && b == binB2) { uint32_t j = atomicAdd(&cB, 1u); if (j < 4096u) bufB[j] = w; }
    }
  }
  for (int i = (P & ~3) + gid; i < P; i += GD * NT) {
    float y; bool m;
    uint32_t w = m2w(yval_u(dren[i], y, m), med);
    uint32_t b = (w >> 17) & 16383u;
    if (b == binA2) { uint32_t j = atomicAdd(&cA, 1u); if (j < 4096u) bufA[j] = w; }
    else if (dv2 && b == binB2) { uint32_t j = atomicAdd(&cB, 1u); if (j < 4096u) bufB[j] = w; }
  }
  __syncthreads();
  if (tid == 0) {
    uint32_t a = cA > 4096u ? 4096u : cA;
    uint32_t b = cB > 4096u ? 4096u : cB;
    cA = a; cB = b;
    baseA = a ? atomicAdd(&WS[W_CNT + 2], a) : 0u;
    baseB = b ? atomicAdd(&WS[W_CNT + 3], b) : 0u;
  }
  __syncthreads();
  for (uint32_t k = tid; k < cA; k += NT)
    if (baseA + k < LCAP) WS[W_LA2 + baseA + k] = bufA[k];
  for (uint32_t k = tid; k < cB; k += NT)
    if (baseB + k < LCAP) WS[W_LB2 + baseB + k] = bufB[k];
}

// kE: redundant dyn; RANSAC scoring (4 candidates/block)
__global__ __launch_bounds__(NT) void kE(uint32_t* __restrict__ WS) {
  const int tid = threadIdx.x, bid = blockIdx.x;
  const int lane = tid & 63, wid = tid >> 6;
  __shared__ uint32_t h512[512], h256[256];
  __shared__ uint32_t wl[4], bc[2];
  __shared__ int ired[16];
  const uint32_t binA2 = WS[W_SB2 + 0], rkA2 = WS[W_SB2 + 1];
  const uint32_t binB2 = WS[W_SB2 + 2], rkB2 = WS[W_SB2 + 3];
  const bool dv2 = (binA2 != binB2);
  uint32_t cA2 = WS[W_CNT + 2]; if (cA2 > LCAP) cA2 = LCAP;
  uint32_t wA = select17(WS + W_LA2, cA2, rkA2, binA2, h512, h256, wl, bc);
  uint32_t wB;
  if (dv2) {
    uint32_t cB2 = WS[W_CNT + 3]; if (cB2 > LCAP) cB2 = LCAP;
    wB = select17(WS + W_LB2, cB2, rkB2, binB2, h512, h256, wl, bc);
  } else {
    wB = select17(WS + W_LA2, cA2, rkB2, binA2, h512, h256, wl, bc);
  }
  float mad = __fmul_rn(__fadd_rn(u2f(wA), u2f(wB)), 0.5f);
  float dyn = __fmul_rn(mad, 0.5f);
  if (dyn < 1e-5f) dyn = 0.01f;   // THRESH
  // scoring
  const float* scales = (const float*)WS + W_SCALES;
  const float* shifts = (const float*)WS + W_SHIFTS;
  const float* x_sub  = (const float*)WS + W_XSUB;
  const float* y_sub  = (const float*)WS + W_YSUB;
  const int cbase = bid * 4;
  float ss[4], tt[4]; int c[4];
#pragma unroll
  for (int j = 0; j < 4; j++) { ss[j] = scales[cbase + j]; tt[j] = shifts[cbase + j]; c[j] = 0; }
  for (int e = tid; e < 50000; e += NT) {
    float xe = x_sub[e], ye = y_sub[e];
#pragma unroll
    for (int j = 0; j < 4; j++) {
      float r = fabsf(__fsub_rn(__fadd_rn(__fmul_rn(ss[j], xe), tt[j]), ye));
      c[j] += (r < dyn) ? 1 : 0;
    }
  }
#pragma unroll
  for (int j = 0; j < 4; j++) {
    int v = c[j];
    for (int off = 32; off > 0; off >>= 1) v += __shfl_down(v, off);
    if (lane == 0) ired[wid * 4 + j] = v;
  }
  __syncthreads();
  if (tid < 4) {
    int tot = ired[tid] + ired[4 + tid] + ired[8 + tid] + ired[12 + tid];
    float sv = scales[cbase + tid];
    ((int*)WS)[W_COUNTS + cbase + tid] = (sv > 0.0f) ? tot : -1;
  }
}

// kF: redundant argmax -> s,t; final elemwise; per-block loss atomicAdd
__global__ __launch_bounds__(NT) void kF(const float* __restrict__ dren,
                                         const float* __restrict__ dpri,
                                         float* __restrict__ out,
                                         uint32_t* __restrict__ WS, int P) {
  const int tid = threadIdx.x, bid = blockIdx.x, gid = bid * NT + tid;
  const int lane = tid & 63, wid = tid >> 6;
  __shared__ int ired[4], iidx[4];
  __shared__ float fbcast[2];
  __shared__ double dred[4];
  // redundant argmax (first occurrence of max)
  {
    const int* counts = (const int*)WS + W_COUNTS;
    const float* scales = (const float*)WS + W_SCALES;
    const float* shifts = (const float*)WS + W_SHIFTS;
    int bcn = -2, bix = 0x7FFFFFFF;
    for (int j = tid; j < 1000; j += NT) {
      int cc = counts[j];
      if (cc > bcn) { bcn = cc; bix = j; }
    }
    for (int off = 32; off > 0; off >>= 1) {
      int oc = __shfl_down(bcn, off), oi = __shfl_down(bix, off);
      if (oc > bcn || (oc == bcn && oi < bix)) { bcn = oc; bix = oi; }
    }
    if (lane == 0) { ired[wid] = bcn; iidx[wid] = bix; }
    __syncthreads();
    if (tid == 0) {
      for (int w = 1; w < 4; w++) {
        if (ired[w] > ired[0] || (ired[w] == ired[0] && iidx[w] < iidx[0])) {
          ired[0] = ired[w]; iidx[0] = iidx[w];
        }
      }
      bool valid = ired[0] >= 0;
      float s = valid ? scales[iidx[0]] : 1.0f;
      float t = valid ? shifts[iidx[0]] : 0.0f;
      uint32_t n = WS[W_N];
      if (n < 10u) { s = 1.0f; t = 0.0f; }
      fbcast[0] = s; fbcast[1] = t;
    }
    __syncthreads();
  }
  const float s = fbcast[0], t = fbcast[1];
  float* out_y = out + 1;
  float* out_depth = out + 1 + P;
  double acc = 0.0;
  const float4* d4 = (const float4*)dren;
  const float4* p4 = (const float4*)dpri;
  const int P4 = P >> 2;
  for (int i = gid; i < P4; i += GF * NT) {
    float4 d = d4[i], p = p4[i];
    float dc[4] = { d.x, d.y, d.z, d.w };
    float pc[4] = { p.x, p.y, p.z, p.w };
#pragma unroll
    for (int k = 0; k < 4; k++) {
      float yv = __fdiv_rn(1.0f, __fadd_rn(dc[k], 1e-6f));
      out_y[4 * i + k] = yv;
      float al = __fadd_rn(__fmul_rn(s, pc[k]), t);
      out_depth[4 * i + k] = __fdiv_rn(1.0f, fmaxf(al, 1e-4f));
      bool m = (dc[k] > 0.1f) && (dc[k] < 100.0f) && isfinite(dc[k]);
      if (m) acc += (double)fabsf(__fsub_rn(al, yv));
    }
  }
  for (int i = (P & ~3) + gid; i < P; i += GF * NT) {
    float dv = dren[i];
    float yv = __fdiv_rn(1.0f, __fadd_rn(dv, 1e-6f));
    out_y[i] = yv;
    float al = __fadd_rn(__fmul_rn(s, dpri[i]), t);
    out_depth[i] = __fdiv_rn(1.0f, fmaxf(al, 1e-4f));
    bool m = (dv > 0.1f) && (dv < 100.0f) && isfinite(dv);
    if (m) acc += (double)fabsf(__fsub_rn(al, yv));
  }
  for (int off = 32; off > 0; off >>= 1) acc += __shfl_down(acc, off);
  __syncthreads();
  if (lane == 0) dred[wid] = acc;
  __syncthreads();
  if (tid == 0)
    atomicAdd((double*)(WS + W_LOSS), dred[0] + dred[1] + dred[2] + dred[3]);
}

// kG: final loss scalar
__global__ void kG(const uint32_t* __restrict__ WS, float* __restrict__ out) {
  if (threadIdx.x == 0 && blockIdx.x == 0) {
    double total = *((const double*)(WS + W_LOSS));
    uint32_t n = WS[W_N];
    uint32_t nd = n ? n : 1u;
    float l1 = __fdiv_rn((float)total, (float)nd);
    out[0] = (n < 100u) ? 0.0f : __fmul_rn(0.5f, l1);
  }
}

// ---------------------------------------------------------------------------
extern "C" void kernel_launch(void* const* d_in, const int* in_sizes, int n_in,
                              void* d_out, int out_size, void* d_ws, size_t ws_size,
                              hipStream_t stream) {
  const float* d_ren = (const float*)d_in[0];
  const float* d_pri = (const float*)d_in[1];
  float* out = (float*)d_out;
  uint32_t* WS = (uint32_t*)d_ws;
  int P = in_sizes[0];

  k_zero<<<(W_ZEND + NT - 1) / NT, NT, 0, stream>>>(WS);
  kA<<<GA, NT, 0, stream>>>(d_ren, WS, P);
  kB<<<GB, NT, 0, stream>>>(d_ren, d_pri, WS, P);
  kC<<<GC, NT, 0, stream>>>(d_ren, WS, P);
  kD<<<GD, NT, 0, stream>>>(d_ren, WS, P);
  kE<<<GE, NT, 0, stream>>>(WS);
  kF<<<GF, NT, 0, stream>>>(d_ren, d_pri, out, WS, P);
  kG<<<1, 64, 0, stream>>>(WS, out);
}

// Round 6
// 281.575 us; speedup vs baseline: 3.0599x; 1.2520x over previous
//
#include <hip/hip_runtime.h>
#include <stdint.h>
#include <math.h>

// ---------------------------------------------------------------------------
// DepthPriorLoss — 10 dispatches, NO in-kernel cross-block sync (fences on
// gfx950 = per-XCD L2 writeback/invalidate = 10x slowdown; dispatch
// boundaries are coherent and cheap). Serial glue steps run in dedicated
// tiny kernels or redundantly per block. Round-5 lesson folded in: one-off
// list selects (median resolution) must NOT be recomputed by every block of
// a wide kernel, and RANSAC scoring must be element-tiled with LDS broadcast
// so candidate loops are compute-bound, not L2-latency-bound.
// All value-visible math identical to the passing round-1 code (threefry
// partitionable PRNG, exact medians, __f*_rn) -> bit-exact outputs.
// ---------------------------------------------------------------------------

#define NT 256
#define GA 1024   // hist1 + valid count
#define GB 512    // bins1 + pairs/subs + collect1
#define GC 1024   // hist2
#define GD 512    // bins2 + collect2
#define GE 256    // scoring: element-sliced, all candidates per block
#define GF 1024   // argmax + final elemwise
#define LCAP 262144u

// word offsets in WS
enum : uint32_t {
  W_CNT  = 0,          // [4] list counters A1,B1,A2,B2
  W_LOSS = 4,          // [2] double (byte 16, 8-aligned)
  W_N    = 6,
  W_VA   = 7, W_VB = 8,   // selected u32 values, median 1
  W_WA   = 9, W_WB = 10,  // selected u32 values, median 2
  W_SB1  = 12,         // binA1, rkA1, binB1, rkB1
  W_SB2  = 16,
  W_COUNTS = 20,       // int[1000] (atomic-accumulated -> must be zeroed)
  W_G1   = 1024,       // uint32[16384]
  W_G2   = 17408,      // uint32[16384]
  W_ZEND = 33792,      // zero everything below this
  W_PERC = 33792,      // uint32[1024]
  W_SCALES = 34816,    // float[1000]
  W_SHIFTS = 35816,    // float[1000]
  W_XSUB = 36816,      // float[50000]
  W_YSUB = 86816,      // float[50000]
  W_LA1  = 136832,     // uint32[LCAP] x 4
  W_LB1  = W_LA1 + LCAP,
  W_LA2  = W_LB1 + LCAP,
  W_LB2  = W_LA2 + LCAP
};

// ---------------- threefry2x32 (JAX-exact, partitionable mode) -------------
__device__ __forceinline__ uint32_t rotl32(uint32_t v, int d) {
  return (v << d) | (v >> (32 - d));
}
__device__ __forceinline__ void tf2x32(uint32_t k0, uint32_t k1,
                                       uint32_t c0, uint32_t c1,
                                       uint32_t& o0, uint32_t& o1) {
  uint32_t ks2 = k0 ^ k1 ^ 0x1BD11BDAu;
  uint32_t x0 = c0 + k0;
  uint32_t x1 = c1 + k1;
#define TFR(r) { x0 += x1; x1 = rotl32(x1, r); x1 ^= x0; }
  TFR(13) TFR(15) TFR(26) TFR(6)
  x0 += k1;  x1 += ks2 + 1u;
  TFR(17) TFR(29) TFR(16) TFR(24)
  x0 += ks2; x1 += k0 + 2u;
  TFR(13) TFR(15) TFR(26) TFR(6)
  x0 += k0;  x1 += k1 + 3u;
  TFR(17) TFR(29) TFR(16) TFR(24)
  x0 += k1;  x1 += ks2 + 4u;
  TFR(13) TFR(15) TFR(26) TFR(6)
  x0 += ks2; x1 += k0 + 5u;
#undef TFR
  o0 = x0; o1 = x1;
}
struct Keys { uint32_t hp0, hp1, lp0, lp1, hs0, hs1, ls0, ls1; };
__device__ __forceinline__ Keys derive_keys() {
  Keys K; uint32_t p0, p1, q0, q1;
  tf2x32(0u, 42u, 0u, 0u, p0, p1);
  tf2x32(0u, 42u, 0u, 1u, q0, q1);
  tf2x32(p0, p1, 0u, 0u, K.hp0, K.hp1);
  tf2x32(p0, p1, 0u, 1u, K.lp0, K.lp1);
  tf2x32(q0, q1, 0u, 0u, K.hs0, K.hs1);
  tf2x32(q0, q1, 0u, 1u, K.ls0, K.ls1);
  return K;
}
__device__ __forceinline__ uint32_t bits32(uint32_t k0, uint32_t k1, uint32_t e) {
  uint32_t a, b; tf2x32(k0, k1, 0u, e, a, b); return a ^ b;
}
__device__ __forceinline__ uint32_t ri_offset(uint32_t hi, uint32_t lo, uint32_t span) {
  uint32_t m = 65536u % span;
  m = (m * m) % span;
  uint32_t off = (hi % span) * m + (lo % span);
  return off % span;
}

// ---------------- order-preserving float<->uint ----------------------------
__device__ __forceinline__ uint32_t f2u(float f) {
  uint32_t u = __float_as_uint(f);
  return (u & 0x80000000u) ? ~u : (u | 0x80000000u);
}
__device__ __forceinline__ float u2f(uint32_t u) {
  uint32_t v = (u & 0x80000000u) ? (u & 0x7FFFFFFFu) : ~u;
  return __uint_as_float(v);
}
__device__ __forceinline__ uint32_t yval_u(float dv, float& y, bool& m) {
  y = __fdiv_rn(1.0f, __fadd_rn(dv, 1e-6f));
  m = (dv > 0.1f) && (dv < 100.0f) && isfinite(dv);
  return m ? f2u(y) : 0xFFFFFFFFu;
}
__device__ __forceinline__ uint32_t m2w(uint32_t u, float med) {
  return (u != 0xFFFFFFFFu) ? f2u(fabsf(__fsub_rn(u2f(u), med))) : 0xFFFFFFFFu;
}
__device__ __forceinline__ float med_from(const uint32_t* WS) {
  return __fmul_rn(__fadd_rn(u2f(WS[W_VA]), u2f(WS[W_VB])), 0.5f);
}

// ---------------- block reduction / scan (256 threads) ---------------------
__device__ __forceinline__ uint32_t block_sum_u32(uint32_t v, uint32_t* wl) {
  const int lane = threadIdx.x & 63, wid = threadIdx.x >> 6;
  for (int off = 32; off > 0; off >>= 1) v += __shfl_down(v, off);
  __syncthreads();
  if (lane == 0) wl[wid] = v;
  __syncthreads();
  return wl[0] + wl[1] + wl[2] + wl[3];
}
__device__ __forceinline__ uint32_t scan_excl(uint32_t local, uint32_t* wl) {
  const int lane = threadIdx.x & 63, wid = threadIdx.x >> 6;
  __syncthreads();
  uint32_t v = local;
#pragma unroll
  for (int off = 1; off < 64; off <<= 1) {
    uint32_t o = __shfl_up(v, off);
    if (lane >= off) v += o;
  }
  if (lane == 63) wl[wid] = v;
  __syncthreads();
  uint32_t base = 0;
  for (int w = 0; w < 4; w++) if (w < wid) base += wl[w];
  return base + v - local;
}

// dual-rank select over a 16384-bin global hist (redundant per block)
__device__ void g_select2(const uint32_t* __restrict__ G, uint32_t rkA, uint32_t rkB,
                          uint32_t* wl, uint32_t* bc4) {
  const int tid = threadIdx.x;
  if (tid < 4) bc4[tid] = 0u;
  __syncthreads();
  uint32_t local = 0;
  for (int k = 0; k < 64; k++) local += G[tid * 64 + k];
  uint32_t excl = scan_excl(local, wl);
  for (int s = 0; s < 2; s++) {
    uint32_t rk = s ? rkB : rkA;
    if (local > 0 && rk >= excl && rk < excl + local) {
      uint32_t c = excl;
      for (int k = 0; k < 64; k++) {
        uint32_t v = G[tid * 64 + k];
        if (rk < c + v) { bc4[2 * s] = (uint32_t)(tid * 64 + k); bc4[2 * s + 1] = rk - c; break; }
        c += v;
      }
    }
  }
  __syncthreads();
}

// exact rank-rk element of a coarse-bin list (single block)
// value = ((16384+bin14)<<17) | (binA<<8) | binB
__device__ uint32_t select17(const uint32_t* __restrict__ L, uint32_t cnt,
                             uint32_t rk, uint32_t bin14,
                             uint32_t* h512, uint32_t* h256,
                             uint32_t* wl, uint32_t* bc) {
  const int tid = threadIdx.x;
  __syncthreads();
  h512[2 * tid] = 0; h512[2 * tid + 1] = 0; h256[tid] = 0;
  if (tid < 2) bc[tid] = 0u;
  __syncthreads();
  for (uint32_t i = tid; i < cnt; i += NT)
    atomicAdd(&h512[(L[i] >> 8) & 511u], 1u);
  __syncthreads();
  uint32_t a0 = h512[2 * tid], a1 = h512[2 * tid + 1];
  uint32_t local = a0 + a1;
  uint32_t excl = scan_excl(local, wl);
  if (local > 0 && rk >= excl && rk < excl + local) {
    if (rk < excl + a0) { bc[0] = (uint32_t)(2 * tid); bc[1] = rk - excl; }
    else { bc[0] = (uint32_t)(2 * tid + 1); bc[1] = rk - excl - a0; }
  }
  __syncthreads();
  uint32_t binA = bc[0], rk2 = bc[1];
  __syncthreads();
  for (uint32_t i = tid; i < cnt; i += NT) {
    uint32_t v = L[i];
    if (((v >> 8) & 511u) == binA) atomicAdd(&h256[v & 255u], 1u);
  }
  __syncthreads();
  uint32_t l2 = h256[tid];
  uint32_t e2 = scan_excl(l2, wl);
  if (l2 > 0 && rk2 >= e2 && rk2 < e2 + l2) bc[0] = (uint32_t)tid;
  __syncthreads();
  uint32_t binB = bc[0];
  __syncthreads();
  return ((16384u + bin14) << 17) | (binA << 8) | binB;
}

// ---------------- kernels --------------------------------------------------
__global__ void k_zero(uint32_t* WS) {
  int i = blockIdx.x * blockDim.x + threadIdx.x;
  if (i < (int)W_ZEND) WS[i] = 0u;
}

// kA: stream dren -> valid count (W_PERC) + coarse hist G1 (packed-u16 LDS)
__global__ __launch_bounds__(NT) void kA(const float* __restrict__ dren,
                                         uint32_t* __restrict__ WS, int P) {
  const int tid = threadIdx.x, bid = blockIdx.x, gid = bid * NT + tid;
  __shared__ uint32_t lh[8192];
  __shared__ uint32_t wl[4];
  for (int i = tid; i < 8192; i += NT) lh[i] = 0u;
  __syncthreads();
  uint32_t cnt = 0;
  const float4* d4 = (const float4*)dren;
  const int P4 = P >> 2;
  for (int i = gid; i < P4; i += GA * NT) {
    float4 d = d4[i];
    float dc[4] = { d.x, d.y, d.z, d.w };
#pragma unroll
    for (int k = 0; k < 4; k++) {
      float y; bool m;
      uint32_t u = yval_u(dc[k], y, m);
      cnt += m ? 1u : 0u;
      uint32_t bin = (u >> 17) & 16383u;
      atomicAdd(&lh[bin >> 1], 1u << ((bin & 1u) << 4));
    }
  }
  for (int i = (P & ~3) + gid; i < P; i += GA * NT) {
    float y; bool m;
    uint32_t u = yval_u(dren[i], y, m);
    cnt += m ? 1u : 0u;
    uint32_t bin = (u >> 17) & 16383u;
    atomicAdd(&lh[bin >> 1], 1u << ((bin & 1u) << 4));
  }
  uint32_t btot = block_sum_u32(cnt, wl);
  if (tid == 0) WS[W_PERC + bid] = btot;
  __syncthreads();
  for (int w = tid; w < 8192; w += NT) {
    uint32_t pv = lh[w];
    if (pv) {
      uint32_t lo = pv & 0xFFFFu, hi = pv >> 16;
      if (lo) atomicAdd(&WS[W_G1 + 2 * w], lo);
      if (hi) atomicAdd(&WS[W_G1 + 2 * w + 1], hi);
    }
  }
}

// kB: redundant n + bins1; pairs + subs; collect median-1 lists
__global__ __launch_bounds__(NT) void kB(const float* __restrict__ dren,
                                         const float* __restrict__ dpri,
                                         uint32_t* __restrict__ WS, int P) {
  const int tid = threadIdx.x, bid = blockIdx.x, gid = bid * NT + tid;
  __shared__ uint32_t bufA[4096], bufB[4096];
  __shared__ uint32_t cA, cB, baseA, baseB;
  __shared__ uint32_t wl[4], bc4[4];
  // redundant n
  uint32_t local = 0;
#pragma unroll
  for (int k = 0; k < 4; k++) local += WS[W_PERC + tid * 4 + k];
  const uint32_t n = block_sum_u32(local, wl);
  const uint32_t nn = n ? n : 1u;
  // redundant coarse bins for median(y)
  g_select2(WS + W_G1, (nn - 1u) >> 1, nn >> 1, wl, bc4);
  const uint32_t binA1 = bc4[0], binB1 = bc4[2];
  const bool dv1 = (binA1 != binB1);
  if (tid == 0) {   // identical-value stores from every block: benign race
    WS[W_N] = n;
    WS[W_SB1 + 0] = bc4[0]; WS[W_SB1 + 1] = bc4[1];
    WS[W_SB1 + 2] = bc4[2]; WS[W_SB1 + 3] = bc4[3];
    cA = 0; cB = 0;
  }
  __syncthreads();
  // pairs + subs
  {
    uint32_t span = n ? n : 1u;
    if (gid < 1000) {
      Keys K = derive_keys();
      uint32_t hi0 = bits32(K.hp0, K.hp1, (uint32_t)(2 * gid));
      uint32_t lo0 = bits32(K.lp0, K.lp1, (uint32_t)(2 * gid));
      uint32_t hi1 = bits32(K.hp0, K.hp1, (uint32_t)(2 * gid + 1));
      uint32_t lo1 = bits32(K.lp0, K.lp1, (uint32_t)(2 * gid + 1));
      uint32_t i0 = ri_offset(hi0, lo0, span);
      uint32_t i1 = ri_offset(hi1, lo1, span);
      float x1v = dpri[i0], x2v = dpri[i1];
      float y1v = __fdiv_rn(1.0f, __fadd_rn(dren[i0], 1e-6f));
      float y2v = __fdiv_rn(1.0f, __fadd_rn(dren[i1], 1e-6f));
      float sc = __fdiv_rn(__fsub_rn(y2v, y1v),
                           __fadd_rn(__fsub_rn(x2v, x1v), 1e-8f));
      ((float*)WS)[W_SCALES + gid] = sc;
      ((float*)WS)[W_SHIFTS + gid] = __fsub_rn(y1v, __fmul_rn(sc, x1v));
    }
    if (gid < 50000) {
      Keys K = derive_keys();
      uint32_t hi = bits32(K.hs0, K.hs1, (uint32_t)gid);
      uint32_t lo = bits32(K.ls0, K.ls1, (uint32_t)gid);
      uint32_t idx = ri_offset(hi, lo, span);
      ((float*)WS)[W_XSUB + gid] = dpri[idx];
      ((float*)WS)[W_YSUB + gid] = __fdiv_rn(1.0f, __fadd_rn(dren[idx], 1e-6f));
    }
  }
  // collect coarse-bin elements (LDS staged, one global atomicAdd per list)
  const float4* d4 = (const float4*)dren;
  const int P4 = P >> 2;
  for (int i = gid; i < P4; i += GB * NT) {
    float4 d = d4[i];
    float dc[4] = { d.x, d.y, d.z, d.w };
#pragma unroll
    for (int k = 0; k < 4; k++) {
      float y; bool m;
      uint32_t u = yval_u(dc[k], y, m);
      uint32_t b = (u >> 17) & 16383u;
      if (b == binA1) { uint32_t j = atomicAdd(&cA, 1u); if (j < 4096u) bufA[j] = u; }
      else if (dv1 && b == binB1) { uint32_t j = atomicAdd(&cB, 1u); if (j < 4096u) bufB[j] = u; }
    }
  }
  for (int i = (P & ~3) + gid; i < P; i += GB * NT) {
    float y; bool m;
    uint32_t u = yval_u(dren[i], y, m);
    uint32_t b = (u >> 17) & 16383u;
    if (b == binA1) { uint32_t j = atomicAdd(&cA, 1u); if (j < 4096u) bufA[j] = u; }
    else if (dv1 && b == binB1) { uint32_t j = atomicAdd(&cB, 1u); if (j < 4096u) bufB[j] = u; }
  }
  __syncthreads();
  if (tid == 0) {
    uint32_t a = cA > 4096u ? 4096u : cA;
    uint32_t b = cB > 4096u ? 4096u : cB;
    cA = a; cB = b;
    baseA = a ? atomicAdd(&WS[W_CNT + 0], a) : 0u;
    baseB = b ? atomicAdd(&WS[W_CNT + 1], b) : 0u;
  }
  __syncthreads();
  for (uint32_t k = tid; k < cA; k += NT)
    if (baseA + k < LCAP) WS[W_LA1 + baseA + k] = bufA[k];
  for (uint32_t k = tid; k < cB; k += NT)
    if (baseB + k < LCAP) WS[W_LB1 + baseB + k] = bufB[k];
}

// kMed: 2 blocks; block b resolves rank b of median(y) -> W_VA / W_VB
__global__ __launch_bounds__(NT) void kMed(uint32_t* __restrict__ WS) {
  const int bid = blockIdx.x;
  __shared__ uint32_t h512[512], h256[256];
  __shared__ uint32_t wl[4], bc[2];
  const uint32_t binA1 = WS[W_SB1 + 0], rkA1 = WS[W_SB1 + 1];
  const uint32_t binB1 = WS[W_SB1 + 2], rkB1 = WS[W_SB1 + 3];
  const bool dv1 = (binA1 != binB1);
  uint32_t bin, rk; const uint32_t* L; uint32_t cnt;
  if (bid == 0) {
    bin = binA1; rk = rkA1; L = WS + W_LA1;
    cnt = WS[W_CNT + 0];
  } else {
    bin = dv1 ? binB1 : binA1; rk = rkB1;
    L = dv1 ? (WS + W_LB1) : (WS + W_LA1);
    cnt = dv1 ? WS[W_CNT + 1] : WS[W_CNT + 0];
  }
  if (cnt > LCAP) cnt = LCAP;
  uint32_t v = select17(L, cnt, rk, bin, h512, h256, wl, bc);
  if (threadIdx.x == 0) WS[bid == 0 ? W_VA : W_VB] = v;
}

// kC: stream hist of |y - med| -> G2
__global__ __launch_bounds__(NT) void kC(const float* __restrict__ dren,
                                         uint32_t* __restrict__ WS, int P) {
  const int tid = threadIdx.x, bid = blockIdx.x, gid = bid * NT + tid;
  __shared__ uint32_t lh[8192];
  const float med = med_from(WS);
  for (int i = tid; i < 8192; i += NT) lh[i] = 0u;
  __syncthreads();
  const float4* d4 = (const float4*)dren;
  const int P4 = P >> 2;
  for (int i = gid; i < P4; i += GC * NT) {
    float4 d = d4[i];
    float dc[4] = { d.x, d.y, d.z, d.w };
#pragma unroll
    for (int k = 0; k < 4; k++) {
      float y; bool m;
      uint32_t w = m2w(yval_u(dc[k], y, m), med);
      uint32_t bin = (w >> 17) & 16383u;
      atomicAdd(&lh[bin >> 1], 1u << ((bin & 1u) << 4));
    }
  }
  for (int i = (P & ~3) + gid; i < P; i += GC * NT) {
    float y; bool m;
    uint32_t w = m2w(yval_u(dren[i], y, m), med);
    uint32_t bin = (w >> 17) & 16383u;
    atomicAdd(&lh[bin >> 1], 1u << ((bin & 1u) << 4));
  }
  __syncthreads();
  for (int w = tid; w < 8192; w += NT) {
    uint32_t pv = lh[w];
    if (pv) {
      uint32_t lo = pv & 0xFFFFu, hi = pv >> 16;
      if (lo) atomicAdd(&WS[W_G2 + 2 * w], lo);
      if (hi) atomicAdd(&WS[W_G2 + 2 * w + 1], hi);
    }
  }
}

// kD: redundant bins2 from G2; collect median-2 lists
__global__ __launch_bounds__(NT) void kD(const float* __restrict__ dren,
                                         uint32_t* __restrict__ WS, int P) {
  const int tid = threadIdx.x, bid = blockIdx.x, gid = bid * NT + tid;
  __shared__ uint32_t bufA[4096], bufB[4096];
  __shared__ uint32_t cA, cB, baseA, baseB;
  __shared__ uint32_t wl[4], bc4[4];
  const float med = med_from(WS);
  const uint32_t n = WS[W_N];
  const uint32_t nn = n ? n : 1u;
  g_select2(WS + W_G2, (nn - 1u) >> 1, nn >> 1, wl, bc4);
  const uint32_t binA2 = bc4[0], binB2 = bc4[2];
  const bool dv2 = (binA2 != binB2);
  if (tid == 0) {
    WS[W_SB2 + 0] = bc4[0]; WS[W_SB2 + 1] = bc4[1];
    WS[W_SB2 + 2] = bc4[2]; WS[W_SB2 + 3] = bc4[3];
    cA = 0; cB = 0;
  }
  __syncthreads();
  const float4* d4 = (const float4*)dren;
  const int P4 = P >> 2;
  for (int i = gid; i < P4; i += GD * NT) {
    float4 d = d4[i];
    float dc[4] = { d.x, d.y, d.z, d.w };
#pragma unroll
    for (int k = 0; k < 4; k++) {
      float y; bool m;
      uint32_t w = m2w(yval_u(dc[k], y, m), med);
      uint32_t b = (w >> 17) & 16383u;
      if (b == binA2) { uint32_t j = atomicAdd(&cA, 1u); if (j < 4096u) bufA[j] = w; }
      else if (dv2 && b == binB2) { uint32_t j = atomicAdd(&cB, 1u); if (j < 4096u) bufB[j] = w; }
    }
  }
  for (int i = (P & ~3) + gid; i < P; i += GD * NT) {
    float y; bool m;
    uint32_t w = m2w(yval_u(dren[i], y, m), med);
    uint32_t b = (w >> 17) & 16383u;
    if (b == binA2) { uint32_t j = atomicAdd(&cA, 1u); if (j < 4096u) bufA[j] = w; }
    else if (dv2 && b == binB2) { uint32_t j = atomicAdd(&cB, 1u); if (j < 4096u) bufB[j] = w; }
  }
  __syncthreads();
  if (tid == 0) {
    uint32_t a = cA > 4096u ? 4096u : cA;
    uint32_t b = cB > 4096u ? 4096u : cB;
    cA = a; cB = b;
    baseA = a ? atomicAdd(&WS[W_CNT + 2], a) : 0u;
    baseB = b ? atomicAdd(&WS[W_CNT + 3], b) : 0u;
  }
  __syncthreads();
  for (uint32_t k = tid; k < cA; k += NT)
    if (baseA + k < LCAP) WS[W_LA2 + baseA + k] = bufA[k];
  for (uint32_t k = tid; k < cB; k += NT)
    if (baseB + k < LCAP) WS[W_LB2 + baseB + k] = bufB[k];
}

// kDyn: 2 blocks; block b resolves rank b of median(|y-med|) -> W_WA / W_WB
__global__ __launch_bounds__(NT) void kDyn(uint32_t* __restrict__ WS) {
  const int bid = blockIdx.x;
  __shared__ uint32_t h512[512], h256[256];
  __shared__ uint32_t wl[4], bc[2];
  const uint32_t binA2 = WS[W_SB2 + 0], rkA2 = WS[W_SB2 + 1];
  const uint32_t binB2 = WS[W_SB2 + 2], rkB2 = WS[W_SB2 + 3];
  const bool dv2 = (binA2 != binB2);
  uint32_t bin, rk; const uint32_t* L; uint32_t cnt;
  if (bid == 0) {
    bin = binA2; rk = rkA2; L = WS + W_LA2;
    cnt = WS[W_CNT + 2];
  } else {
    bin = dv2 ? binB2 : binA2; rk = rkB2;
    L = dv2 ? (WS + W_LB2) : (WS + W_LA2);
    cnt = dv2 ? WS[W_CNT + 3] : WS[W_CNT + 2];
  }
  if (cnt > LCAP) cnt = LCAP;
  uint32_t v = select17(L, cnt, rk, bin, h512, h256, wl, bc);
  if (threadIdx.x == 0) WS[bid == 0 ? W_WA : W_WB] = v;
}

// kE: element-sliced scoring; each block owns ~196 (x,y) in LDS, each thread
// owns 4 candidates; counts accumulated via global atomicAdd (order-free ints)
__global__ __launch_bounds__(NT) void kE(uint32_t* __restrict__ WS) {
  const int tid = threadIdx.x, bid = blockIdx.x;
  __shared__ float lx[200], ly[200];
  // dyn from the two selected values (identical arithmetic everywhere)
  float mad = __fmul_rn(__fadd_rn(u2f(WS[W_WA]), u2f(WS[W_WB])), 0.5f);
  float dyn = __fmul_rn(mad, 0.5f);
  if (dyn < 1e-5f) dyn = 0.01f;   // THRESH
  const int e0 = (bid * 50000) / GE, e1 = ((bid + 1) * 50000) / GE;
  const int cnt = e1 - e0;
  const float* x_sub = (const float*)WS + W_XSUB;
  const float* y_sub = (const float*)WS + W_YSUB;
  if (tid < cnt) { lx[tid] = x_sub[e0 + tid]; ly[tid] = y_sub[e0 + tid]; }
  __syncthreads();
  const float* scales = (const float*)WS + W_SCALES;
  const float* shifts = (const float*)WS + W_SHIFTS;
  float ss[4], tt[4]; int c[4];
#pragma unroll
  for (int j = 0; j < 4; j++) {
    int cand = tid + 256 * j;
    ss[j] = (cand < 1000) ? scales[cand] : 0.0f;
    tt[j] = (cand < 1000) ? shifts[cand] : 0.0f;
    c[j] = 0;
  }
  for (int e = 0; e < cnt; e++) {
    float xe = lx[e], ye = ly[e];   // LDS broadcast: conflict-free
#pragma unroll
    for (int j = 0; j < 4; j++) {
      float r = fabsf(__fsub_rn(__fadd_rn(__fmul_rn(ss[j], xe), tt[j]), ye));
      c[j] += (r < dyn) ? 1 : 0;
    }
  }
  int* counts = (int*)WS + W_COUNTS;
#pragma unroll
  for (int j = 0; j < 4; j++) {
    int cand = tid + 256 * j;
    if (cand < 1000 && c[j] > 0) atomicAdd(&counts[cand], c[j]);
  }
}

// kF: redundant argmax -> s,t; final elemwise; per-block loss atomicAdd
__global__ __launch_bounds__(NT) void kF(const float* __restrict__ dren,
                                         const float* __restrict__ dpri,
                                         float* __restrict__ out,
                                         uint32_t* __restrict__ WS, int P) {
  const int tid = threadIdx.x, bid = blockIdx.x, gid = bid * NT + tid;
  const int lane = tid & 63, wid = tid >> 6;
  __shared__ int ired[4], iidx[4];
  __shared__ float fbcast[2];
  __shared__ double dred[4];
  // redundant argmax (first occurrence of max); apply scale>0 mask here
  {
    const int* counts = (const int*)WS + W_COUNTS;
    const float* scales = (const float*)WS + W_SCALES;
    const float* shifts = (const float*)WS + W_SHIFTS;
    int bcn = -2, bix = 0x7FFFFFFF;
    for (int j = tid; j < 1000; j += NT) {
      int cc = counts[j];
      if (!(scales[j] > 0.0f)) cc = -1;
      if (cc > bcn) { bcn = cc; bix = j; }
    }
    for (int off = 32; off > 0; off >>= 1) {
      int oc = __shfl_down(bcn, off), oi = __shfl_down(bix, off);
      if (oc > bcn || (oc == bcn && oi < bix)) { bcn = oc; bix = oi; }
    }
    if (lane == 0) { ired[wid] = bcn; iidx[wid] = bix; }
    __syncthreads();
    if (tid == 0) {
      for (int w = 1; w < 4; w++) {
        if (ired[w] > ired[0] || (ired[w] == ired[0] && iidx[w] < iidx[0])) {
          ired[0] = ired[w]; iidx[0] = iidx[w];
        }
      }
      bool valid = ired[0] >= 0;
      float s = valid ? scales[iidx[0]] : 1.0f;
      float t = valid ? shifts[iidx[0]] : 0.0f;
      uint32_t n = WS[W_N];
      if (n < 10u) { s = 1.0f; t = 0.0f; }
      fbcast[0] = s; fbcast[1] = t;
    }
    __syncthreads();
  }
  const float s = fbcast[0], t = fbcast[1];
  float* out_y = out + 1;
  float* out_depth = out + 1 + P;
  double acc = 0.0;
  const float4* d4 = (const float4*)dren;
  const float4* p4 = (const float4*)dpri;
  const int P4 = P >> 2;
  for (int i = gid; i < P4; i += GF * NT) {
    float4 d = d4[i], p = p4[i];
    float dc[4] = { d.x, d.y, d.z, d.w };
    float pc[4] = { p.x, p.y, p.z, p.w };
#pragma unroll
    for (int k = 0; k < 4; k++) {
      float yv = __fdiv_rn(1.0f, __fadd_rn(dc[k], 1e-6f));
      out_y[4 * i + k] = yv;
      float al = __fadd_rn(__fmul_rn(s, pc[k]), t);
      out_depth[4 * i + k] = __fdiv_rn(1.0f, fmaxf(al, 1e-4f));
      bool m = (dc[k] > 0.1f) && (dc[k] < 100.0f) && isfinite(dc[k]);
      if (m) acc += (double)fabsf(__fsub_rn(al, yv));
    }
  }
  for (int i = (P & ~3) + gid; i < P; i += GF * NT) {
    float dv = dren[i];
    float yv = __fdiv_rn(1.0f, __fadd_rn(dv, 1e-6f));
    out_y[i] = yv;
    float al = __fadd_rn(__fmul_rn(s, dpri[i]), t);
    out_depth[i] = __fdiv_rn(1.0f, fmaxf(al, 1e-4f));
    bool m = (dv > 0.1f) && (dv < 100.0f) && isfinite(dv);
    if (m) acc += (double)fabsf(__fsub_rn(al, yv));
  }
  for (int off = 32; off > 0; off >>= 1) acc += __shfl_down(acc, off);
  __syncthreads();
  if (lane == 0) dred[wid] = acc;
  __syncthreads();
  if (tid == 0)
    atomicAdd((double*)(WS + W_LOSS), dred[0] + dred[1] + dred[2] + dred[3]);
}

// kG: final loss scalar
__global__ void kG(const uint32_t* __restrict__ WS, float* __restrict__ out) {
  if (threadIdx.x == 0 && blockIdx.x == 0) {
    double total = *((const double*)(WS + W_LOSS));
    uint32_t n = WS[W_N];
    uint32_t nd = n ? n : 1u;
    float l1 = __fdiv_rn((float)total, (float)nd);
    out[0] = (n < 100u) ? 0.0f : __fmul_rn(0.5f, l1);
  }
}

// ---------------------------------------------------------------------------
extern "C" void kernel_launch(void* const* d_in, const int* in_sizes, int n_in,
                              void* d_out, int out_size, void* d_ws, size_t ws_size,
                              hipStream_t stream) {
  const float* d_ren = (const float*)d_in[0];
  const float* d_pri = (const float*)d_in[1];
  float* out = (float*)d_out;
  uint32_t* WS = (uint32_t*)d_ws;
  int P = in_sizes[0];

  k_zero<<<(W_ZEND + NT - 1) / NT, NT, 0, stream>>>(WS);
  kA<<<GA, NT, 0, stream>>>(d_ren, WS, P);
  kB<<<GB, NT, 0, stream>>>(d_ren, d_pri, WS, P);
  kMed<<<2, NT, 0, stream>>>(WS);
  kC<<<GC, NT, 0, stream>>>(d_ren, WS, P);
  kD<<<GD, NT, 0, stream>>>(d_ren, WS, P);
  kDyn<<<2, NT, 0, stream>>>(WS);
  kE<<<GE, NT, 0, stream>>>(WS);
  kF<<<GF, NT, 0, stream>>>(d_ren, d_pri, out, WS, P);
  kG<<<1, 64, 0, stream>>>(WS, out);
}

// Round 7
// 226.161 us; speedup vs baseline: 3.8097x; 1.2450x over previous
//
#include <hip/hip_runtime.h>
#include <stdint.h>
#include <math.h>

// ---------------------------------------------------------------------------
// DepthPriorLoss — 10 dispatches, NO in-kernel cross-block sync.
// Round-6 lesson: the coarse-hist LDS->global flush was 300K device-scope
// atomicAdds concentrated on ~30 cache lines (y=1/d spans ~7 exponents ->
// ~450 hot bins of 16384): ~40us of LLC RMW serialization in kA and kC.
// Fix: hist grids 1024 -> 128 blocks (8x fewer flush atomics); streaming
// 8 MB with 32K threads is still ~3us. All value-visible math identical to
// the passing round-1 code -> bit-exact outputs.
// ---------------------------------------------------------------------------

#define NT 256
#define GA 128    // hist1 + valid count (few blocks: flush-atomic contention)
#define GB 512    // bins1 + pairs/subs + collect1
#define GC 128    // hist2 (same reasoning as GA)
#define GD 512    // bins2 + collect2
#define GE 256    // scoring: element-sliced, all candidates per block
#define GF 1024   // argmax + final elemwise
#define LCAP 262144u

// word offsets in WS
enum : uint32_t {
  W_CNT  = 0,          // [4] list counters A1,B1,A2,B2
  W_LOSS = 4,          // [2] double (byte 16, 8-aligned)
  W_N    = 6,
  W_VA   = 7, W_VB = 8,   // selected u32 values, median 1
  W_WA   = 9, W_WB = 10,  // selected u32 values, median 2
  W_SB1  = 12,         // binA1, rkA1, binB1, rkB1
  W_SB2  = 16,
  W_COUNTS = 20,       // int[1000] (atomic-accumulated -> must be zeroed)
  W_G1   = 1024,       // uint32[16384]
  W_G2   = 17408,      // uint32[16384]
  W_ZEND = 33792,      // zero everything below this
  W_PERC = 33792,      // uint32[GA] per-block valid counts (NOT zeroed)
  W_SCALES = 34816,    // float[1000]
  W_SHIFTS = 35816,    // float[1000]
  W_XSUB = 36816,      // float[50000]
  W_YSUB = 86816,      // float[50000]
  W_LA1  = 136832,     // uint32[LCAP] x 4
  W_LB1  = W_LA1 + LCAP,
  W_LA2  = W_LB1 + LCAP,
  W_LB2  = W_LA2 + LCAP
};

// ---------------- threefry2x32 (JAX-exact, partitionable mode) -------------
__device__ __forceinline__ uint32_t rotl32(uint32_t v, int d) {
  return (v << d) | (v >> (32 - d));
}
__device__ __forceinline__ void tf2x32(uint32_t k0, uint32_t k1,
                                       uint32_t c0, uint32_t c1,
                                       uint32_t& o0, uint32_t& o1) {
  uint32_t ks2 = k0 ^ k1 ^ 0x1BD11BDAu;
  uint32_t x0 = c0 + k0;
  uint32_t x1 = c1 + k1;
#define TFR(r) { x0 += x1; x1 = rotl32(x1, r); x1 ^= x0; }
  TFR(13) TFR(15) TFR(26) TFR(6)
  x0 += k1;  x1 += ks2 + 1u;
  TFR(17) TFR(29) TFR(16) TFR(24)
  x0 += ks2; x1 += k0 + 2u;
  TFR(13) TFR(15) TFR(26) TFR(6)
  x0 += k0;  x1 += k1 + 3u;
  TFR(17) TFR(29) TFR(16) TFR(24)
  x0 += k1;  x1 += ks2 + 4u;
  TFR(13) TFR(15) TFR(26) TFR(6)
  x0 += ks2; x1 += k0 + 5u;
#undef TFR
  o0 = x0; o1 = x1;
}
struct Keys { uint32_t hp0, hp1, lp0, lp1, hs0, hs1, ls0, ls1; };
__device__ __forceinline__ Keys derive_keys() {
  Keys K; uint32_t p0, p1, q0, q1;
  tf2x32(0u, 42u, 0u, 0u, p0, p1);
  tf2x32(0u, 42u, 0u, 1u, q0, q1);
  tf2x32(p0, p1, 0u, 0u, K.hp0, K.hp1);
  tf2x32(p0, p1, 0u, 1u, K.lp0, K.lp1);
  tf2x32(q0, q1, 0u, 0u, K.hs0, K.hs1);
  tf2x32(q0, q1, 0u, 1u, K.ls0, K.ls1);
  return K;
}
__device__ __forceinline__ uint32_t bits32(uint32_t k0, uint32_t k1, uint32_t e) {
  uint32_t a, b; tf2x32(k0, k1, 0u, e, a, b); return a ^ b;
}
__device__ __forceinline__ uint32_t ri_offset(uint32_t hi, uint32_t lo, uint32_t span) {
  uint32_t m = 65536u % span;
  m = (m * m) % span;
  uint32_t off = (hi % span) * m + (lo % span);
  return off % span;
}

// ---------------- order-preserving float<->uint ----------------------------
__device__ __forceinline__ uint32_t f2u(float f) {
  uint32_t u = __float_as_uint(f);
  return (u & 0x80000000u) ? ~u : (u | 0x80000000u);
}
__device__ __forceinline__ float u2f(uint32_t u) {
  uint32_t v = (u & 0x80000000u) ? (u & 0x7FFFFFFFu) : ~u;
  return __uint_as_float(v);
}
__device__ __forceinline__ uint32_t yval_u(float dv, float& y, bool& m) {
  y = __fdiv_rn(1.0f, __fadd_rn(dv, 1e-6f));
  m = (dv > 0.1f) && (dv < 100.0f) && isfinite(dv);
  return m ? f2u(y) : 0xFFFFFFFFu;
}
__device__ __forceinline__ uint32_t m2w(uint32_t u, float med) {
  return (u != 0xFFFFFFFFu) ? f2u(fabsf(__fsub_rn(u2f(u), med))) : 0xFFFFFFFFu;
}
__device__ __forceinline__ float med_from(const uint32_t* WS) {
  return __fmul_rn(__fadd_rn(u2f(WS[W_VA]), u2f(WS[W_VB])), 0.5f);
}

// ---------------- block reduction / scan (256 threads) ---------------------
__device__ __forceinline__ uint32_t block_sum_u32(uint32_t v, uint32_t* wl) {
  const int lane = threadIdx.x & 63, wid = threadIdx.x >> 6;
  for (int off = 32; off > 0; off >>= 1) v += __shfl_down(v, off);
  __syncthreads();
  if (lane == 0) wl[wid] = v;
  __syncthreads();
  return wl[0] + wl[1] + wl[2] + wl[3];
}
__device__ __forceinline__ uint32_t scan_excl(uint32_t local, uint32_t* wl) {
  const int lane = threadIdx.x & 63, wid = threadIdx.x >> 6;
  __syncthreads();
  uint32_t v = local;
#pragma unroll
  for (int off = 1; off < 64; off <<= 1) {
    uint32_t o = __shfl_up(v, off);
    if (lane >= off) v += o;
  }
  if (lane == 63) wl[wid] = v;
  __syncthreads();
  uint32_t base = 0;
  for (int w = 0; w < 4; w++) if (w < wid) base += wl[w];
  return base + v - local;
}

// dual-rank select over a 16384-bin global hist (redundant per block)
__device__ void g_select2(const uint32_t* __restrict__ G, uint32_t rkA, uint32_t rkB,
                          uint32_t* wl, uint32_t* bc4) {
  const int tid = threadIdx.x;
  if (tid < 4) bc4[tid] = 0u;
  __syncthreads();
  uint32_t local = 0;
  for (int k = 0; k < 64; k++) local += G[tid * 64 + k];
  uint32_t excl = scan_excl(local, wl);
  for (int s = 0; s < 2; s++) {
    uint32_t rk = s ? rkB : rkA;
    if (local > 0 && rk >= excl && rk < excl + local) {
      uint32_t c = excl;
      for (int k = 0; k < 64; k++) {
        uint32_t v = G[tid * 64 + k];
        if (rk < c + v) { bc4[2 * s] = (uint32_t)(tid * 64 + k); bc4[2 * s + 1] = rk - c; break; }
        c += v;
      }
    }
  }
  __syncthreads();
}

// exact rank-rk element of a coarse-bin list (single block)
// value = ((16384+bin14)<<17) | (binA<<8) | binB
__device__ uint32_t select17(const uint32_t* __restrict__ L, uint32_t cnt,
                             uint32_t rk, uint32_t bin14,
                             uint32_t* h512, uint32_t* h256,
                             uint32_t* wl, uint32_t* bc) {
  const int tid = threadIdx.x;
  __syncthreads();
  h512[2 * tid] = 0; h512[2 * tid + 1] = 0; h256[tid] = 0;
  if (tid < 2) bc[tid] = 0u;
  __syncthreads();
  for (uint32_t i = tid; i < cnt; i += NT)
    atomicAdd(&h512[(L[i] >> 8) & 511u], 1u);
  __syncthreads();
  uint32_t a0 = h512[2 * tid], a1 = h512[2 * tid + 1];
  uint32_t local = a0 + a1;
  uint32_t excl = scan_excl(local, wl);
  if (local > 0 && rk >= excl && rk < excl + local) {
    if (rk < excl + a0) { bc[0] = (uint32_t)(2 * tid); bc[1] = rk - excl; }
    else { bc[0] = (uint32_t)(2 * tid + 1); bc[1] = rk - excl - a0; }
  }
  __syncthreads();
  uint32_t binA = bc[0], rk2 = bc[1];
  __syncthreads();
  for (uint32_t i = tid; i < cnt; i += NT) {
    uint32_t v = L[i];
    if (((v >> 8) & 511u) == binA) atomicAdd(&h256[v & 255u], 1u);
  }
  __syncthreads();
  uint32_t l2 = h256[tid];
  uint32_t e2 = scan_excl(l2, wl);
  if (l2 > 0 && rk2 >= e2 && rk2 < e2 + l2) bc[0] = (uint32_t)tid;
  __syncthreads();
  uint32_t binB = bc[0];
  __syncthreads();
  return ((16384u + bin14) << 17) | (binA << 8) | binB;
}

// ---------------- kernels --------------------------------------------------
__global__ void k_zero(uint32_t* WS) {
  int i = blockIdx.x * blockDim.x + threadIdx.x;
  if (i < (int)W_ZEND) WS[i] = 0u;
}

// kA: stream dren -> valid count (W_PERC) + coarse hist G1 (packed-u16 LDS)
__global__ __launch_bounds__(NT) void kA(const float* __restrict__ dren,
                                         uint32_t* __restrict__ WS, int P) {
  const int tid = threadIdx.x, bid = blockIdx.x, gid = bid * NT + tid;
  __shared__ uint32_t lh[8192];
  __shared__ uint32_t wl[4];
  for (int i = tid; i < 8192; i += NT) lh[i] = 0u;
  __syncthreads();
  uint32_t cnt = 0;
  const float4* d4 = (const float4*)dren;
  const int P4 = P >> 2;
  for (int i = gid; i < P4; i += GA * NT) {
    float4 d = d4[i];
    float dc[4] = { d.x, d.y, d.z, d.w };
#pragma unroll
    for (int k = 0; k < 4; k++) {
      float y; bool m;
      uint32_t u = yval_u(dc[k], y, m);
      cnt += m ? 1u : 0u;
      uint32_t bin = (u >> 17) & 16383u;
      atomicAdd(&lh[bin >> 1], 1u << ((bin & 1u) << 4));
    }
  }
  for (int i = (P & ~3) + gid; i < P; i += GA * NT) {
    float y; bool m;
    uint32_t u = yval_u(dren[i], y, m);
    cnt += m ? 1u : 0u;
    uint32_t bin = (u >> 17) & 16383u;
    atomicAdd(&lh[bin >> 1], 1u << ((bin & 1u) << 4));
  }
  uint32_t btot = block_sum_u32(cnt, wl);
  if (tid == 0) WS[W_PERC + bid] = btot;
  __syncthreads();
  for (int w = tid; w < 8192; w += NT) {
    uint32_t pv = lh[w];
    if (pv) {
      uint32_t lo = pv & 0xFFFFu, hi = pv >> 16;
      if (lo) atomicAdd(&WS[W_G1 + 2 * w], lo);
      if (hi) atomicAdd(&WS[W_G1 + 2 * w + 1], hi);
    }
  }
}

// kB: redundant n + bins1; pairs + subs; collect median-1 lists
__global__ __launch_bounds__(NT) void kB(const float* __restrict__ dren,
                                         const float* __restrict__ dpri,
                                         uint32_t* __restrict__ WS, int P) {
  const int tid = threadIdx.x, bid = blockIdx.x, gid = bid * NT + tid;
  __shared__ uint32_t bufA[4096], bufB[4096];
  __shared__ uint32_t cA, cB, baseA, baseB;
  __shared__ uint32_t wl[4], bc4[4];
  // redundant n: exactly GA per-block counts exist (rest is poison!)
  uint32_t local = (tid < GA) ? WS[W_PERC + tid] : 0u;
  const uint32_t n = block_sum_u32(local, wl);
  const uint32_t nn = n ? n : 1u;
  // redundant coarse bins for median(y)
  g_select2(WS + W_G1, (nn - 1u) >> 1, nn >> 1, wl, bc4);
  const uint32_t binA1 = bc4[0], binB1 = bc4[2];
  const bool dv1 = (binA1 != binB1);
  if (tid == 0) {   // identical-value stores from every block: benign race
    WS[W_N] = n;
    WS[W_SB1 + 0] = bc4[0]; WS[W_SB1 + 1] = bc4[1];
    WS[W_SB1 + 2] = bc4[2]; WS[W_SB1 + 3] = bc4[3];
    cA = 0; cB = 0;
  }
  __syncthreads();
  // pairs + subs
  {
    uint32_t span = n ? n : 1u;
    if (gid < 1000) {
      Keys K = derive_keys();
      uint32_t hi0 = bits32(K.hp0, K.hp1, (uint32_t)(2 * gid));
      uint32_t lo0 = bits32(K.lp0, K.lp1, (uint32_t)(2 * gid));
      uint32_t hi1 = bits32(K.hp0, K.hp1, (uint32_t)(2 * gid + 1));
      uint32_t lo1 = bits32(K.lp0, K.lp1, (uint32_t)(2 * gid + 1));
      uint32_t i0 = ri_offset(hi0, lo0, span);
      uint32_t i1 = ri_offset(hi1, lo1, span);
      float x1v = dpri[i0], x2v = dpri[i1];
      float y1v = __fdiv_rn(1.0f, __fadd_rn(dren[i0], 1e-6f));
      float y2v = __fdiv_rn(1.0f, __fadd_rn(dren[i1], 1e-6f));
      float sc = __fdiv_rn(__fsub_rn(y2v, y1v),
                           __fadd_rn(__fsub_rn(x2v, x1v), 1e-8f));
      ((float*)WS)[W_SCALES + gid] = sc;
      ((float*)WS)[W_SHIFTS + gid] = __fsub_rn(y1v, __fmul_rn(sc, x1v));
    }
    if (gid < 50000) {
      Keys K = derive_keys();
      uint32_t hi = bits32(K.hs0, K.hs1, (uint32_t)gid);
      uint32_t lo = bits32(K.ls0, K.ls1, (uint32_t)gid);
      uint32_t idx = ri_offset(hi, lo, span);
      ((float*)WS)[W_XSUB + gid] = dpri[idx];
      ((float*)WS)[W_YSUB + gid] = __fdiv_rn(1.0f, __fadd_rn(dren[idx], 1e-6f));
    }
  }
  // collect coarse-bin elements (LDS staged, one global atomicAdd per list)
  const float4* d4 = (const float4*)dren;
  const int P4 = P >> 2;
  for (int i = gid; i < P4; i += GB * NT) {
    float4 d = d4[i];
    float dc[4] = { d.x, d.y, d.z, d.w };
#pragma unroll
    for (int k = 0; k < 4; k++) {
      float y; bool m;
      uint32_t u = yval_u(dc[k], y, m);
      uint32_t b = (u >> 17) & 16383u;
      if (b == binA1) { uint32_t j = atomicAdd(&cA, 1u); if (j < 4096u) bufA[j] = u; }
      else if (dv1 && b == binB1) { uint32_t j = atomicAdd(&cB, 1u); if (j < 4096u) bufB[j] = u; }
    }
  }
  for (int i = (P & ~3) + gid; i < P; i += GB * NT) {
    float y; bool m;
    uint32_t u = yval_u(dren[i], y, m);
    uint32_t b = (u >> 17) & 16383u;
    if (b == binA1) { uint32_t j = atomicAdd(&cA, 1u); if (j < 4096u) bufA[j] = u; }
    else if (dv1 && b == binB1) { uint32_t j = atomicAdd(&cB, 1u); if (j < 4096u) bufB[j] = u; }
  }
  __syncthreads();
  if (tid == 0) {
    uint32_t a = cA > 4096u ? 4096u : cA;
    uint32_t b = cB > 4096u ? 4096u : cB;
    cA = a; cB = b;
    baseA = a ? atomicAdd(&WS[W_CNT + 0], a) : 0u;
    baseB = b ? atomicAdd(&WS[W_CNT + 1], b) : 0u;
  }
  __syncthreads();
  for (uint32_t k = tid; k < cA; k += NT)
    if (baseA + k < LCAP) WS[W_LA1 + baseA + k] = bufA[k];
  for (uint32_t k = tid; k < cB; k += NT)
    if (baseB + k < LCAP) WS[W_LB1 + baseB + k] = bufB[k];
}

// kMed: 2 blocks; block b resolves rank b of median(y) -> W_VA / W_VB
__global__ __launch_bounds__(NT) void kMed(uint32_t* __restrict__ WS) {
  const int bid = blockIdx.x;
  __shared__ uint32_t h512[512], h256[256];
  __shared__ uint32_t wl[4], bc[2];
  const uint32_t binA1 = WS[W_SB1 + 0], rkA1 = WS[W_SB1 + 1];
  const uint32_t binB1 = WS[W_SB1 + 2], rkB1 = WS[W_SB1 + 3];
  const bool dv1 = (binA1 != binB1);
  uint32_t bin, rk; const uint32_t* L; uint32_t cnt;
  if (bid == 0) {
    bin = binA1; rk = rkA1; L = WS + W_LA1;
    cnt = WS[W_CNT + 0];
  } else {
    bin = dv1 ? binB1 : binA1; rk = rkB1;
    L = dv1 ? (WS + W_LB1) : (WS + W_LA1);
    cnt = dv1 ? WS[W_CNT + 1] : WS[W_CNT + 0];
  }
  if (cnt > LCAP) cnt = LCAP;
  uint32_t v = select17(L, cnt, rk, bin, h512, h256, wl, bc);
  if (threadIdx.x == 0) WS[bid == 0 ? W_VA : W_VB] = v;
}

// kC: stream hist of |y - med| -> G2
__global__ __launch_bounds__(NT) void kC(const float* __restrict__ dren,
                                         uint32_t* __restrict__ WS, int P) {
  const int tid = threadIdx.x, bid = blockIdx.x, gid = bid * NT + tid;
  __shared__ uint32_t lh[8192];
  const float med = med_from(WS);
  for (int i = tid; i < 8192; i += NT) lh[i] = 0u;
  __syncthreads();
  const float4* d4 = (const float4*)dren;
  const int P4 = P >> 2;
  for (int i = gid; i < P4; i += GC * NT) {
    float4 d = d4[i];
    float dc[4] = { d.x, d.y, d.z, d.w };
#pragma unroll
    for (int k = 0; k < 4; k++) {
      float y; bool m;
      uint32_t w = m2w(yval_u(dc[k], y, m), med);
      uint32_t bin = (w >> 17) & 16383u;
      atomicAdd(&lh[bin >> 1], 1u << ((bin & 1u) << 4));
    }
  }
  for (int i = (P & ~3) + gid; i < P; i += GC * NT) {
    float y; bool m;
    uint32_t w = m2w(yval_u(dren[i], y, m), med);
    uint32_t bin = (w >> 17) & 16383u;
    atomicAdd(&lh[bin >> 1], 1u << ((bin & 1u) << 4));
  }
  __syncthreads();
  for (int w = tid; w < 8192; w += NT) {
    uint32_t pv = lh[w];
    if (pv) {
      uint32_t lo = pv & 0xFFFFu, hi = pv >> 16;
      if (lo) atomicAdd(&WS[W_G2 + 2 * w], lo);
      if (hi) atomicAdd(&WS[W_G2 + 2 * w + 1], hi);
    }
  }
}

// kD: redundant bins2 from G2; collect median-2 lists
__global__ __launch_bounds__(NT) void kD(const float* __restrict__ dren,
                                         uint32_t* __restrict__ WS, int P) {
  const int tid = threadIdx.x, bid = blockIdx.x, gid = bid * NT + tid;
  __shared__ uint32_t bufA[4096], bufB[4096];
  __shared__ uint32_t cA, cB, baseA, baseB;
  __shared__ uint32_t wl[4], bc4[4];
  const float med = med_from(WS);
  const uint32_t n = WS[W_N];
  const uint32_t nn = n ? n : 1u;
  g_select2(WS + W_G2, (nn - 1u) >> 1, nn >> 1, wl, bc4);
  const uint32_t binA2 = bc4[0], binB2 = bc4[2];
  const bool dv2 = (binA2 != binB2);
  if (tid == 0) {
    WS[W_SB2 + 0] = bc4[0]; WS[W_SB2 + 1] = bc4[1];
    WS[W_SB2 + 2] = bc4[2]; WS[W_SB2 + 3] = bc4[3];
    cA = 0; cB = 0;
  }
  __syncthreads();
  const float4* d4 = (const float4*)dren;
  const int P4 = P >> 2;
  for (int i = gid; i < P4; i += GD * NT) {
    float4 d = d4[i];
    float dc[4] = { d.x, d.y, d.z, d.w };
#pragma unroll
    for (int k = 0; k < 4; k++) {
      float y; bool m;
      uint32_t w = m2w(yval_u(dc[k], y, m), med);
      uint32_t b = (w >> 17) & 16383u;
      if (b == binA2) { uint32_t j = atomicAdd(&cA, 1u); if (j < 4096u) bufA[j] = w; }
      else if (dv2 && b == binB2) { uint32_t j = atomicAdd(&cB, 1u); if (j < 4096u) bufB[j] = w; }
    }
  }
  for (int i = (P & ~3) + gid; i < P; i += GD * NT) {
    float y; bool m;
    uint32_t w = m2w(yval_u(dren[i], y, m), med);
    uint32_t b = (w >> 17) & 16383u;
    if (b == binA2) { uint32_t j = atomicAdd(&cA, 1u); if (j < 4096u) bufA[j] = w; }
    else if (dv2 && b == binB2) { uint32_t j = atomicAdd(&cB, 1u); if (j < 4096u) bufB[j] = w; }
  }
  __syncthreads();
  if (tid == 0) {
    uint32_t a = cA > 4096u ? 4096u : cA;
    uint32_t b = cB > 4096u ? 4096u : cB;
    cA = a; cB = b;
    baseA = a ? atomicAdd(&WS[W_CNT + 2], a) : 0u;
    baseB = b ? atomicAdd(&WS[W_CNT + 3], b) : 0u;
  }
  __syncthreads();
  for (uint32_t k = tid; k < cA; k += NT)
    if (baseA + k < LCAP) WS[W_LA2 + baseA + k] = bufA[k];
  for (uint32_t k = tid; k < cB; k += NT)
    if (baseB + k < LCAP) WS[W_LB2 + baseB + k] = bufB[k];
}

// kDyn: 2 blocks; block b resolves rank b of median(|y-med|) -> W_WA / W_WB
__global__ __launch_bounds__(NT) void kDyn(uint32_t* __restrict__ WS) {
  const int bid = blockIdx.x;
  __shared__ uint32_t h512[512], h256[256];
  __shared__ uint32_t wl[4], bc[2];
  const uint32_t binA2 = WS[W_SB2 + 0], rkA2 = WS[W_SB2 + 1];
  const uint32_t binB2 = WS[W_SB2 + 2], rkB2 = WS[W_SB2 + 3];
  const bool dv2 = (binA2 != binB2);
  uint32_t bin, rk; const uint32_t* L; uint32_t cnt;
  if (bid == 0) {
    bin = binA2; rk = rkA2; L = WS + W_LA2;
    cnt = WS[W_CNT + 2];
  } else {
    bin = dv2 ? binB2 : binA2; rk = rkB2;
    L = dv2 ? (WS + W_LB2) : (WS + W_LA2);
    cnt = dv2 ? WS[W_CNT + 3] : WS[W_CNT + 2];
  }
  if (cnt > LCAP) cnt = LCAP;
  uint32_t v = select17(L, cnt, rk, bin, h512, h256, wl, bc);
  if (threadIdx.x == 0) WS[bid == 0 ? W_WA : W_WB] = v;
}

// kE: element-sliced scoring; each block owns ~196 (x,y) in LDS, each thread
// owns 4 candidates; counts accumulated via global atomicAdd (order-free ints)
__global__ __launch_bounds__(NT) void kE(uint32_t* __restrict__ WS) {
  const int tid = threadIdx.x, bid = blockIdx.x;
  __shared__ float lx[200], ly[200];
  float mad = __fmul_rn(__fadd_rn(u2f(WS[W_WA]), u2f(WS[W_WB])), 0.5f);
  float dyn = __fmul_rn(mad, 0.5f);
  if (dyn < 1e-5f) dyn = 0.01f;   // THRESH
  const int e0 = (bid * 50000) / GE, e1 = ((bid + 1) * 50000) / GE;
  const int cnt = e1 - e0;
  const float* x_sub = (const float*)WS + W_XSUB;
  const float* y_sub = (const float*)WS + W_YSUB;
  if (tid < cnt) { lx[tid] = x_sub[e0 + tid]; ly[tid] = y_sub[e0 + tid]; }
  __syncthreads();
  const float* scales = (const float*)WS + W_SCALES;
  const float* shifts = (const float*)WS + W_SHIFTS;
  float ss[4], tt[4]; int c[4];
#pragma unroll
  for (int j = 0; j < 4; j++) {
    int cand = tid + 256 * j;
    ss[j] = (cand < 1000) ? scales[cand] : 0.0f;
    tt[j] = (cand < 1000) ? shifts[cand] : 0.0f;
    c[j] = 0;
  }
  for (int e = 0; e < cnt; e++) {
    float xe = lx[e], ye = ly[e];   // LDS broadcast: conflict-free
#pragma unroll
    for (int j = 0; j < 4; j++) {
      float r = fabsf(__fsub_rn(__fadd_rn(__fmul_rn(ss[j], xe), tt[j]), ye));
      c[j] += (r < dyn) ? 1 : 0;
    }
  }
  int* counts = (int*)WS + W_COUNTS;
#pragma unroll
  for (int j = 0; j < 4; j++) {
    int cand = tid + 256 * j;
    if (cand < 1000 && c[j] > 0) atomicAdd(&counts[cand], c[j]);
  }
}

// kF: redundant argmax -> s,t; final elemwise; per-block loss atomicAdd
__global__ __launch_bounds__(NT) void kF(const float* __restrict__ dren,
                                         const float* __restrict__ dpri,
                                         float* __restrict__ out,
                                         uint32_t* __restrict__ WS, int P) {
  const int tid = threadIdx.x, bid = blockIdx.x, gid = bid * NT + tid;
  const int lane = tid & 63, wid = tid >> 6;
  __shared__ int ired[4], iidx[4];
  __shared__ float fbcast[2];
  __shared__ double dred[4];
  // redundant argmax (first occurrence of max); apply scale>0 mask here
  {
    const int* counts = (const int*)WS + W_COUNTS;
    const float* scales = (const float*)WS + W_SCALES;
    const float* shifts = (const float*)WS + W_SHIFTS;
    int bcn = -2, bix = 0x7FFFFFFF;
    for (int j = tid; j < 1000; j += NT) {
      int cc = counts[j];
      if (!(scales[j] > 0.0f)) cc = -1;
      if (cc > bcn) { bcn = cc; bix = j; }
    }
    for (int off = 32; off > 0; off >>= 1) {
      int oc = __shfl_down(bcn, off), oi = __shfl_down(bix, off);
      if (oc > bcn || (oc == bcn && oi < bix)) { bcn = oc; bix = oi; }
    }
    if (lane == 0) { ired[wid] = bcn; iidx[wid] = bix; }
    __syncthreads();
    if (tid == 0) {
      for (int w = 1; w < 4; w++) {
        if (ired[w] > ired[0] || (ired[w] == ired[0] && iidx[w] < iidx[0])) {
          ired[0] = ired[w]; iidx[0] = iidx[w];
        }
      }
      bool valid = ired[0] >= 0;
      float s = valid ? scales[iidx[0]] : 1.0f;
      float t = valid ? shifts[iidx[0]] : 0.0f;
      uint32_t n = WS[W_N];
      if (n < 10u) { s = 1.0f; t = 0.0f; }
      fbcast[0] = s; fbcast[1] = t;
    }
    __syncthreads();
  }
  const float s = fbcast[0], t = fbcast[1];
  float* out_y = out + 1;
  float* out_depth = out + 1 + P;
  double acc = 0.0;
  const float4* d4 = (const float4*)dren;
  const float4* p4 = (const float4*)dpri;
  const int P4 = P >> 2;
  for (int i = gid; i < P4; i += GF * NT) {
    float4 d = d4[i], p = p4[i];
    float dc[4] = { d.x, d.y, d.z, d.w };
    float pc[4] = { p.x, p.y, p.z, p.w };
#pragma unroll
    for (int k = 0; k < 4; k++) {
      float yv = __fdiv_rn(1.0f, __fadd_rn(dc[k], 1e-6f));
      out_y[4 * i + k] = yv;
      float al = __fadd_rn(__fmul_rn(s, pc[k]), t);
      out_depth[4 * i + k] = __fdiv_rn(1.0f, fmaxf(al, 1e-4f));
      bool m = (dc[k] > 0.1f) && (dc[k] < 100.0f) && isfinite(dc[k]);
      if (m) acc += (double)fabsf(__fsub_rn(al, yv));
    }
  }
  for (int i = (P & ~3) + gid; i < P; i += GF * NT) {
    float dv = dren[i];
    float yv = __fdiv_rn(1.0f, __fadd_rn(dv, 1e-6f));
    out_y[i] = yv;
    float al = __fadd_rn(__fmul_rn(s, dpri[i]), t);
    out_depth[i] = __fdiv_rn(1.0f, fmaxf(al, 1e-4f));
    bool m = (dv > 0.1f) && (dv < 100.0f) && isfinite(dv);
    if (m) acc += (double)fabsf(__fsub_rn(al, yv));
  }
  for (int off = 32; off > 0; off >>= 1) acc += __shfl_down(acc, off);
  __syncthreads();
  if (lane == 0) dred[wid] = acc;
  __syncthreads();
  if (tid == 0)
    atomicAdd((double*)(WS + W_LOSS), dred[0] + dred[1] + dred[2] + dred[3]);
}

// kG: final loss scalar
__global__ void kG(const uint32_t* __restrict__ WS, float* __restrict__ out) {
  if (threadIdx.x == 0 && blockIdx.x == 0) {
    double total = *((const double*)(WS + W_LOSS));
    uint32_t n = WS[W_N];
    uint32_t nd = n ? n : 1u;
    float l1 = __fdiv_rn((float)total, (float)nd);
    out[0] = (n < 100u) ? 0.0f : __fmul_rn(0.5f, l1);
  }
}

// ---------------------------------------------------------------------------
extern "C" void kernel_launch(void* const* d_in, const int* in_sizes, int n_in,
                              void* d_out, int out_size, void* d_ws, size_t ws_size,
                              hipStream_t stream) {
  const float* d_ren = (const float*)d_in[0];
  const float* d_pri = (const float*)d_in[1];
  float* out = (float*)d_out;
  uint32_t* WS = (uint32_t*)d_ws;
  int P = in_sizes[0];

  k_zero<<<(W_ZEND + NT - 1) / NT, NT, 0, stream>>>(WS);
  kA<<<GA, NT, 0, stream>>>(d_ren, WS, P);
  kB<<<GB, NT, 0, stream>>>(d_ren, d_pri, WS, P);
  kMed<<<2, NT, 0, stream>>>(WS);
  kC<<<GC, NT, 0, stream>>>(d_ren, WS, P);
  kD<<<GD, NT, 0, stream>>>(d_ren, WS, P);
  kDyn<<<2, NT, 0, stream>>>(WS);
  kE<<<GE, NT, 0, stream>>>(WS);
  kF<<<GF, NT, 0, stream>>>(d_ren, d_pri, out, WS, P);
  kG<<<1, 64, 0, stream>>>(WS, out);
}